// Round 9
// baseline (256.535 us; speedup 1.0000x reference)
//
#include <hip/hip_runtime.h>
#include <cstdint>
#include <cstddef>

#define N_NODES 12288
#define B_EX    64
#define R_REG   36
#define E_EDGES 196608
#define DD_IN   512
#define DD_OUT  512
#define P_DIM   256
#define D_IMG   1024
#define TANH_C  2.885390081777927f   // 2*log2(e)

// A2 concatenated GEMM operand: [12288][1024] bf16 : neigh | h1
#define A2_LD     1024
#define NEIGH_OFF 0
#define H1_OFF    512

typedef unsigned short ushort;
typedef __bf16 bf16x8 __attribute__((ext_vector_type(8)));
typedef float f32x4 __attribute__((ext_vector_type(4)));
typedef ushort ushort4v __attribute__((ext_vector_type(4)));
typedef ushort ushort8v __attribute__((ext_vector_type(8)));

__device__ __forceinline__ ushort f2bf(float f) {
    uint32_t u = __float_as_uint(f);
    uint32_t r = (u + 0x7fffu + ((u >> 16) & 1u)) >> 16;
    return (ushort)r;
}
__device__ __forceinline__ float bf2f(ushort u) {
    return __uint_as_float(((uint32_t)u) << 16);
}
__device__ __forceinline__ void gload_lds16(const void* g, void* l) {
    __builtin_amdgcn_global_load_lds((const __attribute__((address_space(1))) void*)g,
                                     (__attribute__((address_space(3))) void*)l, 16, 0, 0);
}
__device__ __forceinline__ float fexp2(float x) {
    float r; asm("v_exp_f32 %0, %1" : "=v"(r) : "v"(x)); return r;
}
__device__ __forceinline__ float frcp(float x) {
    float r; asm("v_rcp_f32 %0, %1" : "=v"(r) : "v"(x)); return r;
}
// bijective XCD swizzle for nwg % 8 == 0 (identity otherwise)
__device__ __forceinline__ int xcd_swz(int lin, int nwg) {
    if ((nwg & 7) == 0) return (lin & 7) * (nwg >> 3) + (lin >> 3);
    return lin;
}

// ================= bf16 MFMA GEMM: C = [Cadd +] A @ BT^T + bias =================
template<bool HAS_BIAS, bool ADD_C, bool RELU, bool OUT_F32, bool OUT_BF16>
__global__ __launch_bounds__(256) void gemm_bf16mfma(
    const ushort* __restrict__ A, const ushort* __restrict__ BT,
    const float* __restrict__ bias, const float* __restrict__ Cadd,
    float* __restrict__ Cf, ushort* __restrict__ Cb,
    int M, int Nn, int K, int ldb, int coloff)
{
    __shared__ ushort As[128 * 64];
    __shared__ ushort Bs[128 * 64];
    const int tid = threadIdx.x;
    const int lane = tid & 63;
    const int wid = tid >> 6;
    const int wm = wid >> 1, wn = wid & 1;
    const int nx = gridDim.x;
    const int lin = xcd_swz(blockIdx.y * nx + blockIdx.x, nx * gridDim.y);
    const int m0 = (lin / nx) * 128, n0 = (lin % nx) * 128;

    f32x4 acc[4][4] = {};

    const int srow = tid >> 3;
    const int schk = tid & 7;
    const char* AsB = (const char*)As;
    const char* BsB = (const char*)Bs;

    for (int k0 = 0; k0 < K; k0 += 64) {
#pragma unroll
        for (int i = 0; i < 4; ++i) {
            int row = i * 32 + srow;
            int ca = (schk ^ (row & 7)) * 8;
            gload_lds16(A + (size_t)(m0 + row) * K + k0 + ca,
                        (char*)As + i * 4096 + wid * 1024);
            gload_lds16(BT + (size_t)(n0 + row) * K + k0 + ca,
                        (char*)Bs + i * 4096 + wid * 1024);
        }
        __syncthreads();
#pragma unroll
        for (int kk = 0; kk < 2; ++kk) {
            const int kc = kk * 4 + (lane >> 4);
            bf16x8 af[4], bfr[4];
#pragma unroll
            for (int i = 0; i < 4; ++i) {
                int row = wm * 64 + i * 16 + (lane & 15);
                af[i] = *(const bf16x8*)(AsB + row * 128 + ((kc ^ (row & 7)) << 4));
            }
#pragma unroll
            for (int j = 0; j < 4; ++j) {
                int col = wn * 64 + j * 16 + (lane & 15);
                bfr[j] = *(const bf16x8*)(BsB + col * 128 + ((kc ^ (col & 7)) << 4));
            }
#pragma unroll
            for (int i = 0; i < 4; ++i)
#pragma unroll
                for (int j = 0; j < 4; ++j)
                    acc[i][j] = __builtin_amdgcn_mfma_f32_16x16x32_bf16(af[i], bfr[j], acc[i][j], 0, 0, 0);
        }
        __syncthreads();
    }

#pragma unroll
    for (int i = 0; i < 4; ++i) {
#pragma unroll
        for (int j = 0; j < 4; ++j) {
#pragma unroll
            for (int q = 0; q < 4; ++q) {
                int row = m0 + wm * 64 + i * 16 + (lane >> 4) * 4 + q;
                int col = n0 + wn * 64 + j * 16 + (lane & 15);
                float v = acc[i][j][q];
                if (HAS_BIAS) v += bias[col];
                if (ADD_C)    v += Cadd[(size_t)row * Nn + col];
                if (RELU)     v = fmaxf(v, 0.f);
                if (OUT_F32)  Cf[(size_t)row * Nn + col] = v;
                if (OUT_BF16) Cb[(size_t)row * ldb + col + coloff] = f2bf(v);
            }
        }
    }
}

// ========== final GEMM: out = relu(A2 @ BT2^T + imgz + b'), BM=128 BN=64, K=1024 ====
// grid (8, 96) = 768 blocks = exactly 3/CU.
__global__ __launch_bounds__(256) void gemm_out(
    const ushort* __restrict__ A, const ushort* __restrict__ BT,
    const float* __restrict__ bias, const float* __restrict__ Cadd,
    float* __restrict__ Cf)
{
    __shared__ ushort As[128 * 64];
    __shared__ ushort Bs[64 * 64];
    const int K = A2_LD;
    const int tid = threadIdx.x;
    const int lane = tid & 63;
    const int wid = tid >> 6;
    const int lin = xcd_swz(blockIdx.y * 8 + blockIdx.x, 768);
    const int m0 = (lin >> 3) * 128, n0 = (lin & 7) * 64;

    f32x4 acc[2][4] = {};

    const int srow = tid >> 3;
    const int schk = tid & 7;
    const char* AsB = (const char*)As;
    const char* BsB = (const char*)Bs;

    for (int k0 = 0; k0 < K; k0 += 64) {
#pragma unroll
        for (int i = 0; i < 4; ++i) {
            int row = i * 32 + srow;
            int ca = (schk ^ (row & 7)) * 8;
            gload_lds16(A + (size_t)(m0 + row) * K + k0 + ca,
                        (char*)As + i * 4096 + wid * 1024);
        }
#pragma unroll
        for (int i = 0; i < 2; ++i) {
            int row = i * 32 + srow;
            int cb = (schk ^ (row & 7)) * 8;
            gload_lds16(BT + (size_t)(n0 + row) * K + k0 + cb,
                        (char*)Bs + i * 4096 + wid * 1024);
        }
        __syncthreads();
#pragma unroll
        for (int kk = 0; kk < 2; ++kk) {
            const int kc = kk * 4 + (lane >> 4);
            bf16x8 af[2], bfr[4];
#pragma unroll
            for (int i = 0; i < 2; ++i) {
                int row = wid * 32 + i * 16 + (lane & 15);
                af[i] = *(const bf16x8*)(AsB + row * 128 + ((kc ^ (row & 7)) << 4));
            }
#pragma unroll
            for (int j = 0; j < 4; ++j) {
                int col = j * 16 + (lane & 15);
                bfr[j] = *(const bf16x8*)(BsB + col * 128 + ((kc ^ (col & 7)) << 4));
            }
#pragma unroll
            for (int i = 0; i < 2; ++i)
#pragma unroll
                for (int j = 0; j < 4; ++j)
                    acc[i][j] = __builtin_amdgcn_mfma_f32_16x16x32_bf16(af[i], bfr[j], acc[i][j], 0, 0, 0);
        }
        __syncthreads();
    }

#pragma unroll
    for (int i = 0; i < 2; ++i) {
#pragma unroll
        for (int j = 0; j < 4; ++j) {
#pragma unroll
            for (int q = 0; q < 4; ++q) {
                int row = m0 + wid * 32 + i * 16 + (lane >> 4) * 4 + q;
                int col = n0 + j * 16 + (lane & 15);
                float v = acc[i][j][q] + bias[col] + Cadd[(size_t)row * DD_OUT + col];
                Cf[(size_t)row * DD_OUT + col] = fmaxf(v, 0.f);
            }
        }
    }
}

// ========== fused first GEMM: A=h_bf [12288][512], BT=[WfT;WnT] [768][512] ==========
__global__ __launch_bounds__(256) void gemm_fused_first(
    const ushort* __restrict__ A, const ushort* __restrict__ BT,
    const float* __restrict__ biasF, const float* __restrict__ biasN,
    float* __restrict__ node_proj_s, ushort* __restrict__ A2)
{
    __shared__ ushort As[128 * 64];
    __shared__ ushort Bs[128 * 64];
    const int K = DD_IN;
    const int tid = threadIdx.x;
    const int lane = tid & 63;
    const int wid = tid >> 6;
    const int wm = wid >> 1, wn = wid & 1;
    const int nx = gridDim.x;
    const int lin = xcd_swz(blockIdx.y * nx + blockIdx.x, nx * gridDim.y);
    const int m0 = (lin / nx) * 128, n0 = (lin % nx) * 128;

    f32x4 acc[4][4] = {};

    const int srow = tid >> 3;
    const int schk = tid & 7;
    const char* AsB = (const char*)As;
    const char* BsB = (const char*)Bs;

    for (int k0 = 0; k0 < K; k0 += 64) {
#pragma unroll
        for (int i = 0; i < 4; ++i) {
            int row = i * 32 + srow;
            int ca = (schk ^ (row & 7)) * 8;
            gload_lds16(A + (size_t)(m0 + row) * K + k0 + ca,
                        (char*)As + i * 4096 + wid * 1024);
            gload_lds16(BT + (size_t)(n0 + row) * K + k0 + ca,
                        (char*)Bs + i * 4096 + wid * 1024);
        }
        __syncthreads();
#pragma unroll
        for (int kk = 0; kk < 2; ++kk) {
            const int kc = kk * 4 + (lane >> 4);
            bf16x8 af[4], bfr[4];
#pragma unroll
            for (int i = 0; i < 4; ++i) {
                int row = wm * 64 + i * 16 + (lane & 15);
                af[i] = *(const bf16x8*)(AsB + row * 128 + ((kc ^ (row & 7)) << 4));
            }
#pragma unroll
            for (int j = 0; j < 4; ++j) {
                int col = wn * 64 + j * 16 + (lane & 15);
                bfr[j] = *(const bf16x8*)(BsB + col * 128 + ((kc ^ (col & 7)) << 4));
            }
#pragma unroll
            for (int i = 0; i < 4; ++i)
#pragma unroll
                for (int j = 0; j < 4; ++j)
                    acc[i][j] = __builtin_amdgcn_mfma_f32_16x16x32_bf16(af[i], bfr[j], acc[i][j], 0, 0, 0);
        }
        __syncthreads();
    }

    if (n0 < 256) {
#pragma unroll
        for (int i = 0; i < 4; ++i)
#pragma unroll
            for (int j = 0; j < 4; ++j)
#pragma unroll
                for (int q = 0; q < 4; ++q) {
                    int row = m0 + wm * 64 + i * 16 + (lane >> 4) * 4 + q;
                    int col = n0 + wn * 64 + j * 16 + (lane & 15);
                    node_proj_s[(size_t)row * P_DIM + col] = (acc[i][j][q] + biasF[col]) * TANH_C;
                }
    } else {
#pragma unroll
        for (int i = 0; i < 4; ++i)
#pragma unroll
            for (int j = 0; j < 4; ++j)
#pragma unroll
                for (int q = 0; q < 4; ++q) {
                    int row = m0 + wm * 64 + i * 16 + (lane >> 4) * 4 + q;
                    int col = n0 - 256 + wn * 64 + j * 16 + (lane & 15);
                    A2[(size_t)row * A2_LD + H1_OFF + col] = f2bf(acc[i][j][q] + biasN[col]);
                }
    }
}

// ======== preamble: fp32->bf16 converts + weight transposes + counter zero ========
#define CVT_N1 (N_NODES * DD_IN / 4)
#define CVT_N2 (CVT_N1 + B_EX * R_REG * D_IMG / 4)
#define CVT_N3 (CVT_N2 + D_IMG * DD_OUT / 4)
#define CVT_BLKS  (CVT_N3 / 256)          // 8960
#define TR_BLKS   352
#define ZERO_INTS (2 * N_NODES + 2 * B_EX)  // 24704
#define ZERO_BLKS ((ZERO_INTS + 255) / 256) // 97
__global__ __launch_bounds__(256) void preamble(
    const float* __restrict__ h, const float* __restrict__ imgf,
    const float* __restrict__ Wim,
    ushort* __restrict__ h_bf, ushort* __restrict__ imgf_bf, ushort* __restrict__ Wim_bf,
    const float* __restrict__ Wf, const float* __restrict__ Wn,
    const float* __restrict__ Wi, const float* __restrict__ Wap,
    ushort* __restrict__ WfnT, ushort* __restrict__ WiT,
    ushort* __restrict__ Wap1T, ushort* __restrict__ BT2,
    int* __restrict__ zero_p)
{
    if (blockIdx.x < CVT_BLKS) {
        int i = blockIdx.x * 256 + threadIdx.x;
        const float4* src; ushort4v* dst; int j;
        if (i < CVT_N1)      { src = (const float4*)h;    dst = (ushort4v*)h_bf;    j = i; }
        else if (i < CVT_N2) { src = (const float4*)imgf; dst = (ushort4v*)imgf_bf; j = i - CVT_N1; }
        else                 { src = (const float4*)Wim;  dst = (ushort4v*)Wim_bf;  j = i - CVT_N2; }
        float4 v = src[j];
        ushort4v o;
        o[0] = f2bf(v.x); o[1] = f2bf(v.y); o[2] = f2bf(v.z); o[3] = f2bf(v.w);
        dst[j] = o;
        return;
    }
    if (blockIdx.x >= CVT_BLKS + TR_BLKS) {
        int i = (blockIdx.x - CVT_BLKS - TR_BLKS) * 256 + threadIdx.x;
        if (i < ZERO_INTS) zero_p[i] = 0;
        return;
    }
    // ---- transpose tiles ----
    int t = blockIdx.x - CVT_BLKS;
    const float* W; ushort* WT; int N, ldt, gx;
    if (t < 32)       { W = Wf;  WT = WfnT;                        N = 256; ldt = 512;  gx = 4; }
    else if (t < 96)  { W = Wn;  WT = WfnT + 256 * 512;            N = 512; ldt = 512;  gx = 8; t -= 32; }
    else if (t < 160) { W = Wi;  WT = WiT;                         N = 256; ldt = 1024; gx = 4; t -= 96; }
    else if (t < 224) { W = Wap; WT = Wap1T;                       N = 512; ldt = 512;  gx = 8; t -= 160; }
    else if (t < 288) { W = Wap; WT = BT2 + NEIGH_OFF;             N = 512; ldt = 1024; gx = 8; t -= 224; }
    else              { W = Wap + 512 * 512; WT = BT2 + H1_OFF;    N = 512; ldt = 1024; gx = 8; t -= 288; }
    const int n0 = (t % gx) * 64, k0 = (t / gx) * 64;

    __shared__ float tt[64][65];
    const int tx = threadIdx.x & 15, ty = threadIdx.x >> 4;
#pragma unroll
    for (int r = 0; r < 4; ++r) {
        float4 v = *(const float4*)&W[(size_t)(k0 + ty * 4 + r) * N + n0 + tx * 4];
        tt[ty * 4 + r][tx * 4 + 0] = v.x;
        tt[ty * 4 + r][tx * 4 + 1] = v.y;
        tt[ty * 4 + r][tx * 4 + 2] = v.z;
        tt[ty * 4 + r][tx * 4 + 3] = v.w;
    }
    __syncthreads();
    const int nl = threadIdx.x >> 2, kq = (threadIdx.x & 3) * 16;
    ushort u[16] __attribute__((aligned(16)));
#pragma unroll
    for (int c = 0; c < 16; ++c) u[c] = f2bf(tt[kq + c][nl]);
    ushort* d = &WT[(size_t)(n0 + nl) * ldt + k0 + kq];
    *(ushort8v*)d = *(ushort8v*)&u[0];
    *(ushort8v*)(d + 8) = *(ushort8v*)&u[8];
}

// ================= fused counting (edges by dst + nodes by batch) =================
__global__ __launch_bounds__(256) void count_all(
    const int* __restrict__ dst, const int* __restrict__ bid,
    int* __restrict__ deg, int* __restrict__ bcnt)
{
    int b = blockIdx.x;
    if (b < E_EDGES / 256) {
        atomicAdd(&deg[dst[b * 256 + threadIdx.x]], 1);
    } else {
        atomicAdd(&bcnt[bid[(b - E_EDGES / 256) * 256 + threadIdx.x]], 1);
    }
}

// ================= fused scans + bprime =================
__global__ __launch_bounds__(256) void scan_all(
    const int* __restrict__ deg, int* __restrict__ offs,
    const int* __restrict__ bcnt, int* __restrict__ boffs,
    const float* __restrict__ bim, const float* __restrict__ Wap,
    const float* __restrict__ bap, float* __restrict__ bp)
{
    const int t = threadIdx.x;
    if (blockIdx.x == 0) {
        __shared__ int s[257];
        const int base = t * 48;
        int sum = 0;
        for (int j = 0; j < 48; ++j) sum += deg[base + j];
        s[t] = sum;
        __syncthreads();
        if (t == 0) {
            int acc = 0;
            for (int i = 0; i < 256; ++i) { int v = s[i]; s[i] = acc; acc += v; }
            s[256] = acc;
        }
        __syncthreads();
        int run = s[t];
        for (int j = 0; j < 48; ++j) { offs[base + j] = run; run += deg[base + j]; }
        if (t == 255) offs[N_NODES] = s[256];
    } else if (blockIdx.x == 1) {
        if (t == 0) {
            int acc = 0;
            for (int i = 0; i < B_EX; ++i) { boffs[i] = acc; acc += bcnt[i]; }
            boffs[B_EX] = acc;
        }
    } else {
        int n = (blockIdx.x - 2) * 256 + t;
        float s = bap[n];
        for (int k = 0; k < DD_OUT; ++k) s += bim[k] * Wap[(size_t)k * DD_OUT + n];
        bp[n] = s;
    }
}

// ================= fused scatter (edges + nodes) =================
__global__ __launch_bounds__(256) void scatter_all(
    const int* __restrict__ src, const int* __restrict__ dst,
    const int* __restrict__ offs, int* __restrict__ cur, int* __restrict__ ssrc,
    const int* __restrict__ bid, const int* __restrict__ boffs,
    int* __restrict__ bcur, int* __restrict__ nlist)
{
    int b = blockIdx.x;
    if (b < E_EDGES / 256) {
        int i = b * 256 + threadIdx.x;
        int d = dst[i];
        int p = offs[d] + atomicAdd(&cur[d], 1);
        ssrc[p] = src[i];
    } else {
        int i = (b - E_EDGES / 256) * 256 + threadIdx.x;
        int e = bid[i];
        int p = boffs[e] + atomicAdd(&bcur[e], 1);
        nlist[p] = i;
    }
}

// ================= attention logits + softmax =================
__global__ __launch_bounds__(128, 4) void att_kernel(
    const float* __restrict__ node_proj_s, const float* __restrict__ img_proj,
    const int* __restrict__ batch_ids, const float* __restrict__ Wa,
    float* __restrict__ att)
{
    __shared__ float red[2][R_REG][68];
    const int wv = threadIdx.x >> 6;
    const int n = blockIdx.x * 2 + wv;
    const int lane = threadIdx.x & 63;
    const int b = batch_ids[n];

    const float4 nps = *(const float4*)(node_proj_s + (size_t)n * P_DIM + 4 * lane);
    const float4 wa = *(const float4*)(Wa + 4 * lane);
    const float* ip0 = img_proj + (size_t)b * R_REG * P_DIM + 4 * lane;

#pragma unroll
    for (int r = 0; r < R_REG; ++r) {
        float4 ip = *(const float4*)(ip0 + (size_t)r * P_DIM);
        float t0 = fexp2(fmaf(ip.x, TANH_C, nps.x));
        float t1 = fexp2(fmaf(ip.y, TANH_C, nps.y));
        float t2 = fexp2(fmaf(ip.z, TANH_C, nps.z));
        float t3 = fexp2(fmaf(ip.w, TANH_C, nps.w));
        float p;
        p = wa.x * frcp(t0 + 1.f);
        p = fmaf(wa.y, frcp(t1 + 1.f), p);
        p = fmaf(wa.z, frcp(t2 + 1.f), p);
        p = fmaf(wa.w, frcp(t3 + 1.f), p);
        red[wv][r][lane] = p;
    }
    __syncthreads();

    float logit = -INFINITY;
    if (lane < R_REG) {
        const float* row = &red[wv][lane][0];
        float4 s4 = *(const float4*)row;
#pragma unroll
        for (int c = 4; c < 64; c += 4) {
            float4 v = *(const float4*)(row + c);
            s4.x += v.x; s4.y += v.y; s4.z += v.z; s4.w += v.w;
        }
        logit = -2.f * ((s4.x + s4.y) + (s4.z + s4.w));
    }
    float m = logit;
#pragma unroll
    for (int off = 32; off; off >>= 1) m = fmaxf(m, __shfl_xor(m, off));
    float e = (lane < R_REG) ? __expf(logit - m) : 0.f;
    float s = e;
#pragma unroll
    for (int off = 32; off; off >>= 1) s += __shfl_xor(s, off);
    if (lane < R_REG) att[(size_t)n * R_REG + lane] = e / s;
}

// ======= batched attended Z-feature: imgz[n] = sum_r att[n][r] * Z[b][r] (512c f32) ====
#define IA_SLICES 16
__global__ __launch_bounds__(256) void img_att_batched(
    const float* __restrict__ att, const ushort* __restrict__ Z,
    const int* __restrict__ boffs, const int* __restrict__ nlist,
    float* __restrict__ imgz)
{
    const int b     = blockIdx.x & 63;
    const int slice = blockIdx.x >> 6;
    const int t = threadIdx.x;
    const int c0 = 2 * t;

    const int ns = boffs[b], ne = boffs[b + 1];
    const int cnt = ne - ns;
    const int per = (cnt + IA_SLICES - 1) / IA_SLICES;
    const int i0 = ns + slice * per;
    const int i1 = min(i0 + per, ne);
    if (i0 >= i1) return;

    float2 col[R_REG];
    const ushort* base = Z + (size_t)b * R_REG * DD_OUT + c0;
#pragma unroll
    for (int r = 0; r < R_REG; ++r) {
        ushort2 u = *(const ushort2*)(base + (size_t)r * DD_OUT);
        col[r].x = bf2f(u.x); col[r].y = bf2f(u.y);
    }

    __shared__ float att_s[8][R_REG];
    for (int i = i0; i < i1; i += 8) {
        int g = min(8, i1 - i);
        __syncthreads();
        for (int idx = t; idx < g * R_REG; idx += 256) {
            int j = idx / R_REG, r = idx - j * R_REG;
            att_s[j][r] = att[(size_t)nlist[i + j] * R_REG + r];
        }
        __syncthreads();
        for (int j = 0; j < g; ++j) {
            float4 av[9];
#pragma unroll
            for (int q = 0; q < 9; ++q) av[q] = *(const float4*)&att_s[j][q * 4];
            float ax = 0.f, ay = 0.f;
#pragma unroll
            for (int r = 0; r < R_REG; ++r) {
                float a = (r & 2) ? ((r & 1) ? av[r >> 2].w : av[r >> 2].z)
                                  : ((r & 1) ? av[r >> 2].y : av[r >> 2].x);
                ax += a * col[r].x;
                ay += a * col[r].y;
            }
            float2 o; o.x = ax; o.y = ay;
            *(float2*)&imgz[(size_t)nlist[i + j] * DD_OUT + c0] = o;
        }
    }
}

// ================= CSR gather: wave per node, lane = 8 cols (uint4), unroll x2 ====
__device__ __forceinline__ void acc8(float* a, uint4 v) {
    a[0] += bf2f((ushort)(v.x & 0xffffu)); a[1] += bf2f((ushort)(v.x >> 16));
    a[2] += bf2f((ushort)(v.y & 0xffffu)); a[3] += bf2f((ushort)(v.y >> 16));
    a[4] += bf2f((ushort)(v.z & 0xffffu)); a[5] += bf2f((ushort)(v.z >> 16));
    a[6] += bf2f((ushort)(v.w & 0xffffu)); a[7] += bf2f((ushort)(v.w >> 16));
}

__global__ __launch_bounds__(256) void gather_neigh(
    const int* __restrict__ off, const int* __restrict__ ssrc,
    const ushort* __restrict__ A2h1 /* A2 + H1_OFF */,
    ushort* __restrict__ A2nb /* A2 + NEIGH_OFF */)
{
    const int wv = threadIdx.x >> 6;
    const int n = blockIdx.x * 4 + wv;
    const int lane = threadIdx.x & 63;
    const int e0 = off[n], e1 = off[n + 1];

    float a[8] = {};
    int e = e0;
    for (; e + 2 <= e1; e += 2) {
        int s0 = ssrc[e], s1 = ssrc[e + 1];
        uint4 v0 = *(const uint4*)(A2h1 + (size_t)s0 * A2_LD + lane * 8);
        uint4 v1 = *(const uint4*)(A2h1 + (size_t)s1 * A2_LD + lane * 8);
        acc8(a, v0);
        acc8(a, v1);
    }
    if (e < e1) {
        int s0 = ssrc[e];
        uint4 v0 = *(const uint4*)(A2h1 + (size_t)s0 * A2_LD + lane * 8);
        acc8(a, v0);
    }
    ushort8v o;
#pragma unroll
    for (int i = 0; i < 8; ++i) o[i] = f2bf(a[i]);
    *(ushort8v*)(A2nb + (size_t)n * A2_LD + lane * 8) = o;
}

extern "C" void kernel_launch(void* const* d_in, const int* in_sizes, int n_in,
                              void* d_out, int out_size, void* d_ws, size_t ws_size,
                              hipStream_t stream) {
    const float* h         = (const float*)d_in[0];
    const float* img_feats = (const float*)d_in[1];
    const int*   batch_ids = (const int*)d_in[2];
    const int*   src       = (const int*)d_in[3];
    const int*   dst       = (const int*)d_in[4];
    const float* Wf  = (const float*)d_in[5];
    const float* bf  = (const float*)d_in[6];
    const float* Wi  = (const float*)d_in[7];
    const float* bi  = (const float*)d_in[8];
    const float* Wa  = (const float*)d_in[9];
    // d_in[10] = ba: constant logit shift, cancels in softmax
    const float* Wn  = (const float*)d_in[11];
    const float* bn  = (const float*)d_in[12];
    const float* Wim = (const float*)d_in[13];
    const float* bim = (const float*)d_in[14];
    const float* Wap = (const float*)d_in[15];
    const float* bap = (const float*)d_in[16];
    float* out = (float*)d_out;
    float* ws  = (float*)d_ws;

    // ---- workspace layout (offsets in 4-byte words) ----
    ushort* h_bf    = (ushort*)(ws + 0);          // [12288][512] bf16   (3145728 w)
    ushort* A2      = (ushort*)(ws + 3145728);    // [12288][1024] bf16: neigh|h1 (6291456 w)
    float*  imgz    = ws + 9437184;               // [12288][512] f32    (6291456 w)
    float*  node_proj = ws + 15728640;            // [12288][256] f32 pre-scaled (3145728 w)
    float*  img_proj  = ws + 18874368;            // [2304][256]  f32    (589824 w)
    ushort* imgf_bf   = (ushort*)(ws + 19464192); // [2304][1024] bf16   (1179648 w)
    float*  att       = ws + 20643840;            // [12288][36]  f32    (442368 w)
    ushort* Z      = (ushort*)(ws + 21086208);    // [2304][512] bf16    (589824 w)
    ushort* WfnT   = (ushort*)(ws + 21676032);    // [768][512]          (196608 w)
    ushort* WiT    = (ushort*)(ws + 21872640);    // [256][1024]         (131072 w)
    ushort* Wim_bf = (ushort*)(ws + 22003712);    // [1024][512]         (262144 w)
    ushort* Wap1T  = (ushort*)(ws + 22265856);    // [512][512]          (131072 w)
    ushort* WpT    = (ushort*)(ws + 22396928);    // [512][1024] W'^T    (262144 w)
    ushort* BT2    = (ushort*)(ws + 22659072);    // [512][1024]: Wap1^T|Wap2^T (262144 w)
    float*  bprime = ws + 22921216;               // [512]
    // zeroed region (contiguous): deg, cur, bcnt, bcur
    int* deg  = (int*)(ws + 22921728);            // [12288]
    int* cur  = deg + N_NODES;                    // [12288]
    int* bcnt = cur + N_NODES;                    // [64]
    int* bcur = bcnt + B_EX;                      // [64]
    int* offs = bcur + B_EX;                      // [12289]
    int* boffs = offs + N_NODES + 1;              // [65]
    int* ssrc = boffs + B_EX + 1;                 // [196608]
    int* nlist = ssrc + E_EDGES;                  // [12288]

    dim3 blk(256);

    // ---- preamble: converts + transposes + zero counters ----
    preamble<<<dim3(CVT_BLKS + TR_BLKS + ZERO_BLKS), blk, 0, stream>>>(
        h, img_feats, Wim, h_bf, imgf_bf, Wim_bf,
        Wf, Wn, Wi, Wap, WfnT, WiT, Wap1T, BT2, deg);

    // ---- CSR build + batch sort ----
    count_all<<<dim3(E_EDGES / 256 + N_NODES / 256), blk, 0, stream>>>(dst, batch_ids, deg, bcnt);
    scan_all<<<dim3(4), blk, 0, stream>>>(deg, offs, bcnt, boffs, bim, Wap, bap, bprime);
    scatter_all<<<dim3(E_EDGES / 256 + N_NODES / 256), blk, 0, stream>>>(
        src, dst, offs, cur, ssrc, batch_ids, boffs, bcur, nlist);

    // ---- W'^T = Wap1^T @ Wim^T -> WpT [512][1024] ----
    gemm_bf16mfma<false, false, false, false, true><<<dim3(D_IMG / 128, DD_OUT / 128), blk, 0, stream>>>(
        Wap1T, Wim_bf, nullptr, nullptr, nullptr, WpT, DD_OUT, D_IMG, DD_OUT, D_IMG, 0);
    // ---- Z = imgf_bf @ W' -> [2304][512] bf16 ----
    gemm_bf16mfma<false, false, false, false, true><<<dim3(DD_OUT / 128, (B_EX * R_REG) / 128), blk, 0, stream>>>(
        imgf_bf, WpT, nullptr, nullptr, nullptr, Z, B_EX * R_REG, DD_OUT, D_IMG, DD_OUT, 0);

    // ---- fused: node_proj_s (scaled) + h1 -> A2 h1 cols ----
    gemm_fused_first<<<dim3((P_DIM + DD_OUT) / 128, N_NODES / 128), blk, 0, stream>>>(
        h_bf, WfnT, bf, bn, node_proj, A2);
    // ---- img_proj = img_feats @ Wi + bi ----
    gemm_bf16mfma<true, false, false, true, false><<<dim3(P_DIM / 128, (B_EX * R_REG) / 128), blk, 0, stream>>>(
        imgf_bf, WiT, bi, nullptr, img_proj, nullptr, B_EX * R_REG, P_DIM, D_IMG, 0, 0);
    // ---- attention ----
    att_kernel<<<dim3(N_NODES / 2), dim3(128), 0, stream>>>(node_proj, img_proj, batch_ids, Wa, att);
    img_att_batched<<<dim3(B_EX * IA_SLICES), blk, 0, stream>>>(att, Z, boffs, nlist, imgz);
    // ---- neigh = segment_sum(h1[src], dst) -> A2 neigh cols ----
    gather_neigh<<<dim3(N_NODES / 4), blk, 0, stream>>>(offs, ssrc, A2 + H1_OFF, A2 + NEIGH_OFF);
    // ---- out = relu(A2 @ [Wap1; Wap2] + imgz + b') ----
    gemm_out<<<dim3(8, 96), blk, 0, stream>>>(A2, BT2, bprime, imgz, out);
}

// Round 10
// 249.732 us; speedup vs baseline: 1.0272x; 1.0272x over previous
//
#include <hip/hip_runtime.h>
#include <cstdint>
#include <cstddef>

#define N_NODES 12288
#define B_EX    64
#define R_REG   36
#define E_EDGES 196608
#define DD_IN   512
#define DD_OUT  512
#define P_DIM   256
#define D_IMG   1024
#define TANH_C  2.885390081777927f   // 2*log2(e)

// A2 concatenated GEMM operand: [12288][1024] bf16 : neigh | h1
#define A2_LD     1024
#define NEIGH_OFF 0
#define H1_OFF    512

typedef unsigned short ushort;
typedef __bf16 bf16x8 __attribute__((ext_vector_type(8)));
typedef float f32x4 __attribute__((ext_vector_type(4)));
typedef ushort ushort4v __attribute__((ext_vector_type(4)));
typedef ushort ushort8v __attribute__((ext_vector_type(8)));

__device__ __forceinline__ ushort f2bf(float f) {
    uint32_t u = __float_as_uint(f);
    uint32_t r = (u + 0x7fffu + ((u >> 16) & 1u)) >> 16;
    return (ushort)r;
}
__device__ __forceinline__ float bf2f(ushort u) {
    return __uint_as_float(((uint32_t)u) << 16);
}
__device__ __forceinline__ void gload_lds16(const void* g, void* l) {
    __builtin_amdgcn_global_load_lds((const __attribute__((address_space(1))) void*)g,
                                     (__attribute__((address_space(3))) void*)l, 16, 0, 0);
}
// reg-staged f32 -> bf16 LDS fill: reads 8 f32, writes one 16B bf16 chunk.
// Drop-in replacement for one lane's gload_lds16 (same source-chunk->LDS mapping).
__device__ __forceinline__ void stage_f32(const float* __restrict__ src, void* ldsDst) {
    float4 v0 = *(const float4*)src;
    float4 v1 = *(const float4*)(src + 4);
    ushort8v o;
    o[0] = f2bf(v0.x); o[1] = f2bf(v0.y); o[2] = f2bf(v0.z); o[3] = f2bf(v0.w);
    o[4] = f2bf(v1.x); o[5] = f2bf(v1.y); o[6] = f2bf(v1.z); o[7] = f2bf(v1.w);
    *(ushort8v*)ldsDst = o;
}
__device__ __forceinline__ float fexp2(float x) {
    float r; asm("v_exp_f32 %0, %1" : "=v"(r) : "v"(x)); return r;
}
__device__ __forceinline__ float frcp(float x) {
    float r; asm("v_rcp_f32 %0, %1" : "=v"(r) : "v"(x)); return r;
}
// bijective XCD swizzle for nwg % 8 == 0 (identity otherwise)
__device__ __forceinline__ int xcd_swz(int lin, int nwg) {
    if ((nwg & 7) == 0) return (lin & 7) * (nwg >> 3) + (lin >> 3);
    return lin;
}

// ========== gemm_wp: W'^T = Wap1T @ Wim^T -> WiZT rows 256..767 ==========
// A = Wap1T [512][512] bf16 (gload), BT = Wim f32 [1024][512] (reg-staged). grid (8,4).
__global__ __launch_bounds__(256) void gemm_wp(
    const ushort* __restrict__ A, const float* __restrict__ BTf,
    ushort* __restrict__ WiZT)
{
    __shared__ ushort As[128 * 64];
    __shared__ ushort Bs[128 * 64];
    const int K = DD_IN;
    const int tid = threadIdx.x;
    const int lane = tid & 63;
    const int wid = tid >> 6;
    const int wm = wid >> 1, wn = wid & 1;
    const int lin = blockIdx.y * 8 + blockIdx.x;
    const int m0 = (lin >> 3) * 128, n0 = (lin & 7) * 128;

    f32x4 acc[4][4] = {};
    const int srow = tid >> 3;
    const int schk = tid & 7;
    const char* AsB = (const char*)As;
    const char* BsB = (const char*)Bs;

    for (int k0 = 0; k0 < K; k0 += 64) {
#pragma unroll
        for (int i = 0; i < 4; ++i) {
            int row = i * 32 + srow;
            int ca = (schk ^ (row & 7)) * 8;
            gload_lds16(A + (size_t)(m0 + row) * K + k0 + ca,
                        (char*)As + i * 4096 + wid * 1024);
            stage_f32(BTf + (size_t)(n0 + row) * K + k0 + ca,
                      (char*)Bs + i * 4096 + wid * 1024 + lane * 16);
        }
        __syncthreads();
#pragma unroll
        for (int kk = 0; kk < 2; ++kk) {
            const int kc = kk * 4 + (lane >> 4);
            bf16x8 af[4], bfr[4];
#pragma unroll
            for (int i = 0; i < 4; ++i) {
                int row = wm * 64 + i * 16 + (lane & 15);
                af[i] = *(const bf16x8*)(AsB + row * 128 + ((kc ^ (row & 7)) << 4));
            }
#pragma unroll
            for (int j = 0; j < 4; ++j) {
                int col = wn * 64 + j * 16 + (lane & 15);
                bfr[j] = *(const bf16x8*)(BsB + col * 128 + ((kc ^ (col & 7)) << 4));
            }
#pragma unroll
            for (int i = 0; i < 4; ++i)
#pragma unroll
                for (int j = 0; j < 4; ++j)
                    acc[i][j] = __builtin_amdgcn_mfma_f32_16x16x32_bf16(af[i], bfr[j], acc[i][j], 0, 0, 0);
        }
        __syncthreads();
    }

#pragma unroll
    for (int i = 0; i < 4; ++i)
#pragma unroll
        for (int j = 0; j < 4; ++j)
#pragma unroll
            for (int q = 0; q < 4; ++q) {
                int row = m0 + wm * 64 + i * 16 + (lane >> 4) * 4 + q;   // W' col 0..511
                int col = n0 + wn * 64 + j * 16 + (lane & 15);           // W' row 0..1023
                WiZT[(size_t)(256 + row) * D_IMG + col] = f2bf(acc[i][j][q]);
            }
}

// ========== gemm_imgz: A = img_feats f32 [2304][1024] (reg-staged), BT = WiZT [768][1024]
// cols 0..255  -> img_proj f32 (+bi); cols 256..767 -> Z bf16 [2304][512]. grid (6,18).
__global__ __launch_bounds__(256) void gemm_imgz(
    const float* __restrict__ Af, const ushort* __restrict__ BT,
    const float* __restrict__ bi, float* __restrict__ img_proj,
    ushort* __restrict__ Z)
{
    __shared__ ushort As[128 * 64];
    __shared__ ushort Bs[128 * 64];
    const int K = D_IMG;
    const int tid = threadIdx.x;
    const int lane = tid & 63;
    const int wid = tid >> 6;
    const int wm = wid >> 1, wn = wid & 1;
    const int lin = blockIdx.y * 6 + blockIdx.x;
    const int m0 = (lin / 6) * 128, n0 = (lin % 6) * 128;

    f32x4 acc[4][4] = {};
    const int srow = tid >> 3;
    const int schk = tid & 7;
    const char* AsB = (const char*)As;
    const char* BsB = (const char*)Bs;

    for (int k0 = 0; k0 < K; k0 += 64) {
#pragma unroll
        for (int i = 0; i < 4; ++i) {
            int row = i * 32 + srow;
            int ca = (schk ^ (row & 7)) * 8;
            stage_f32(Af + (size_t)(m0 + row) * K + k0 + ca,
                      (char*)As + i * 4096 + wid * 1024 + lane * 16);
            gload_lds16(BT + (size_t)(n0 + row) * K + k0 + ca,
                        (char*)Bs + i * 4096 + wid * 1024);
        }
        __syncthreads();
#pragma unroll
        for (int kk = 0; kk < 2; ++kk) {
            const int kc = kk * 4 + (lane >> 4);
            bf16x8 af[4], bfr[4];
#pragma unroll
            for (int i = 0; i < 4; ++i) {
                int row = wm * 64 + i * 16 + (lane & 15);
                af[i] = *(const bf16x8*)(AsB + row * 128 + ((kc ^ (row & 7)) << 4));
            }
#pragma unroll
            for (int j = 0; j < 4; ++j) {
                int col = wn * 64 + j * 16 + (lane & 15);
                bfr[j] = *(const bf16x8*)(BsB + col * 128 + ((kc ^ (col & 7)) << 4));
            }
#pragma unroll
            for (int i = 0; i < 4; ++i)
#pragma unroll
                for (int j = 0; j < 4; ++j)
                    acc[i][j] = __builtin_amdgcn_mfma_f32_16x16x32_bf16(af[i], bfr[j], acc[i][j], 0, 0, 0);
        }
        __syncthreads();
    }

    if (n0 < 256) {
#pragma unroll
        for (int i = 0; i < 4; ++i)
#pragma unroll
            for (int j = 0; j < 4; ++j)
#pragma unroll
                for (int q = 0; q < 4; ++q) {
                    int row = m0 + wm * 64 + i * 16 + (lane >> 4) * 4 + q;
                    int col = n0 + wn * 64 + j * 16 + (lane & 15);
                    img_proj[(size_t)row * P_DIM + col] = acc[i][j][q] + bi[col];
                }
    } else {
#pragma unroll
        for (int i = 0; i < 4; ++i)
#pragma unroll
            for (int j = 0; j < 4; ++j)
#pragma unroll
                for (int q = 0; q < 4; ++q) {
                    int row = m0 + wm * 64 + i * 16 + (lane >> 4) * 4 + q;
                    int col = n0 - 256 + wn * 64 + j * 16 + (lane & 15);
                    Z[(size_t)row * DD_OUT + col] = f2bf(acc[i][j][q]);
                }
    }
}

// ========== fused first GEMM: A = h f32 [12288][512] (reg-staged), BT=[WfT;WnT] ==========
// cols 0..255 -> node_proj_s = (acc+bf)*TANH_C f32; cols 256..767 -> A2 h1 bf16. grid (6,96).
__global__ __launch_bounds__(256) void gemm_fused_first(
    const float* __restrict__ Af, const ushort* __restrict__ BT,
    const float* __restrict__ biasF, const float* __restrict__ biasN,
    float* __restrict__ node_proj_s, ushort* __restrict__ A2)
{
    __shared__ ushort As[128 * 64];
    __shared__ ushort Bs[128 * 64];
    const int K = DD_IN;
    const int tid = threadIdx.x;
    const int lane = tid & 63;
    const int wid = tid >> 6;
    const int wm = wid >> 1, wn = wid & 1;
    const int lin = xcd_swz(blockIdx.y * 6 + blockIdx.x, 576);
    const int m0 = (lin / 6) * 128, n0 = (lin % 6) * 128;

    f32x4 acc[4][4] = {};
    const int srow = tid >> 3;
    const int schk = tid & 7;
    const char* AsB = (const char*)As;
    const char* BsB = (const char*)Bs;

    for (int k0 = 0; k0 < K; k0 += 64) {
#pragma unroll
        for (int i = 0; i < 4; ++i) {
            int row = i * 32 + srow;
            int ca = (schk ^ (row & 7)) * 8;
            stage_f32(Af + (size_t)(m0 + row) * K + k0 + ca,
                      (char*)As + i * 4096 + wid * 1024 + lane * 16);
            gload_lds16(BT + (size_t)(n0 + row) * K + k0 + ca,
                        (char*)Bs + i * 4096 + wid * 1024);
        }
        __syncthreads();
#pragma unroll
        for (int kk = 0; kk < 2; ++kk) {
            const int kc = kk * 4 + (lane >> 4);
            bf16x8 af[4], bfr[4];
#pragma unroll
            for (int i = 0; i < 4; ++i) {
                int row = wm * 64 + i * 16 + (lane & 15);
                af[i] = *(const bf16x8*)(AsB + row * 128 + ((kc ^ (row & 7)) << 4));
            }
#pragma unroll
            for (int j = 0; j < 4; ++j) {
                int col = wn * 64 + j * 16 + (lane & 15);
                bfr[j] = *(const bf16x8*)(BsB + col * 128 + ((kc ^ (col & 7)) << 4));
            }
#pragma unroll
            for (int i = 0; i < 4; ++i)
#pragma unroll
                for (int j = 0; j < 4; ++j)
                    acc[i][j] = __builtin_amdgcn_mfma_f32_16x16x32_bf16(af[i], bfr[j], acc[i][j], 0, 0, 0);
        }
        __syncthreads();
    }

    if (n0 < 256) {
#pragma unroll
        for (int i = 0; i < 4; ++i)
#pragma unroll
            for (int j = 0; j < 4; ++j)
#pragma unroll
                for (int q = 0; q < 4; ++q) {
                    int row = m0 + wm * 64 + i * 16 + (lane >> 4) * 4 + q;
                    int col = n0 + wn * 64 + j * 16 + (lane & 15);
                    node_proj_s[(size_t)row * P_DIM + col] = (acc[i][j][q] + biasF[col]) * TANH_C;
                }
    } else {
#pragma unroll
        for (int i = 0; i < 4; ++i)
#pragma unroll
            for (int j = 0; j < 4; ++j)
#pragma unroll
                for (int q = 0; q < 4; ++q) {
                    int row = m0 + wm * 64 + i * 16 + (lane >> 4) * 4 + q;
                    int col = n0 - 256 + wn * 64 + j * 16 + (lane & 15);
                    A2[(size_t)row * A2_LD + H1_OFF + col] = f2bf(acc[i][j][q] + biasN[col]);
                }
    }
}

// ========== final GEMM: out = relu(A2 @ BT2^T + imgz + b'), BM=128 BN=64, K=1024 ====
__global__ __launch_bounds__(256) void gemm_out(
    const ushort* __restrict__ A, const ushort* __restrict__ BT,
    const float* __restrict__ bias, const float* __restrict__ Cadd,
    float* __restrict__ Cf)
{
    __shared__ ushort As[128 * 64];
    __shared__ ushort Bs[64 * 64];
    const int K = A2_LD;
    const int tid = threadIdx.x;
    const int lane = tid & 63;
    const int wid = tid >> 6;
    const int lin = xcd_swz(blockIdx.y * 8 + blockIdx.x, 768);
    const int m0 = (lin >> 3) * 128, n0 = (lin & 7) * 64;

    f32x4 acc[2][4] = {};
    const int srow = tid >> 3;
    const int schk = tid & 7;
    const char* AsB = (const char*)As;
    const char* BsB = (const char*)Bs;

    for (int k0 = 0; k0 < K; k0 += 64) {
#pragma unroll
        for (int i = 0; i < 4; ++i) {
            int row = i * 32 + srow;
            int ca = (schk ^ (row & 7)) * 8;
            gload_lds16(A + (size_t)(m0 + row) * K + k0 + ca,
                        (char*)As + i * 4096 + wid * 1024);
        }
#pragma unroll
        for (int i = 0; i < 2; ++i) {
            int row = i * 32 + srow;
            int cb = (schk ^ (row & 7)) * 8;
            gload_lds16(BT + (size_t)(n0 + row) * K + k0 + cb,
                        (char*)Bs + i * 4096 + wid * 1024);
        }
        __syncthreads();
#pragma unroll
        for (int kk = 0; kk < 2; ++kk) {
            const int kc = kk * 4 + (lane >> 4);
            bf16x8 af[2], bfr[4];
#pragma unroll
            for (int i = 0; i < 2; ++i) {
                int row = wid * 32 + i * 16 + (lane & 15);
                af[i] = *(const bf16x8*)(AsB + row * 128 + ((kc ^ (row & 7)) << 4));
            }
#pragma unroll
            for (int j = 0; j < 4; ++j) {
                int col = j * 16 + (lane & 15);
                bfr[j] = *(const bf16x8*)(BsB + col * 128 + ((kc ^ (col & 7)) << 4));
            }
#pragma unroll
            for (int i = 0; i < 2; ++i)
#pragma unroll
                for (int j = 0; j < 4; ++j)
                    acc[i][j] = __builtin_amdgcn_mfma_f32_16x16x32_bf16(af[i], bfr[j], acc[i][j], 0, 0, 0);
        }
        __syncthreads();
    }

#pragma unroll
    for (int i = 0; i < 2; ++i)
#pragma unroll
        for (int j = 0; j < 4; ++j)
#pragma unroll
            for (int q = 0; q < 4; ++q) {
                int row = m0 + wid * 32 + i * 16 + (lane >> 4) * 4 + q;
                int col = n0 + j * 16 + (lane & 15);
                float v = acc[i][j][q] + bias[col] + Cadd[(size_t)row * DD_OUT + col];
                Cf[(size_t)row * DD_OUT + col] = fmaxf(v, 0.f);
            }
}

// ======== preamble: weight transposes + counter zero (converts eliminated) ========
#define TR_BLKS   352
#define ZERO_INTS (2 * N_NODES + 2 * B_EX)  // 24704
#define ZERO_BLKS ((ZERO_INTS + 255) / 256) // 97
__global__ __launch_bounds__(256) void preamble(
    const float* __restrict__ Wf, const float* __restrict__ Wn,
    const float* __restrict__ Wi, const float* __restrict__ Wap,
    ushort* __restrict__ WfnT, ushort* __restrict__ WiZT,
    ushort* __restrict__ Wap1T, ushort* __restrict__ BT2,
    int* __restrict__ zero_p)
{
    if (blockIdx.x >= TR_BLKS) {
        int i = (blockIdx.x - TR_BLKS) * 256 + threadIdx.x;
        if (i < ZERO_INTS) zero_p[i] = 0;
        return;
    }
    int t = blockIdx.x;
    const float* W; ushort* WT; int N, ldt, gx;
    if (t < 32)       { W = Wf;  WT = WfnT;                        N = 256; ldt = 512;  gx = 4; }
    else if (t < 96)  { W = Wn;  WT = WfnT + 256 * 512;            N = 512; ldt = 512;  gx = 8; t -= 32; }
    else if (t < 160) { W = Wi;  WT = WiZT;                        N = 256; ldt = 1024; gx = 4; t -= 96; }
    else if (t < 224) { W = Wap; WT = Wap1T;                       N = 512; ldt = 512;  gx = 8; t -= 160; }
    else if (t < 288) { W = Wap; WT = BT2 + NEIGH_OFF;             N = 512; ldt = 1024; gx = 8; t -= 224; }
    else              { W = Wap + 512 * 512; WT = BT2 + H1_OFF;    N = 512; ldt = 1024; gx = 8; t -= 288; }
    const int n0 = (t % gx) * 64, k0 = (t / gx) * 64;

    __shared__ float tt[64][65];
    const int tx = threadIdx.x & 15, ty = threadIdx.x >> 4;
#pragma unroll
    for (int r = 0; r < 4; ++r) {
        float4 v = *(const float4*)&W[(size_t)(k0 + ty * 4 + r) * N + n0 + tx * 4];
        tt[ty * 4 + r][tx * 4 + 0] = v.x;
        tt[ty * 4 + r][tx * 4 + 1] = v.y;
        tt[ty * 4 + r][tx * 4 + 2] = v.z;
        tt[ty * 4 + r][tx * 4 + 3] = v.w;
    }
    __syncthreads();
    const int nl = threadIdx.x >> 2, kq = (threadIdx.x & 3) * 16;
    ushort u[16] __attribute__((aligned(16)));
#pragma unroll
    for (int c = 0; c < 16; ++c) u[c] = f2bf(tt[kq + c][nl]);
    ushort* d = &WT[(size_t)(n0 + nl) * ldt + k0 + kq];
    *(ushort8v*)d = *(ushort8v*)&u[0];
    *(ushort8v*)(d + 8) = *(ushort8v*)&u[8];
}

// ================= fused counting (edges by dst + nodes by batch) =================
__global__ __launch_bounds__(256) void count_all(
    const int* __restrict__ dst, const int* __restrict__ bid,
    int* __restrict__ deg, int* __restrict__ bcnt)
{
    int b = blockIdx.x;
    if (b < E_EDGES / 256) {
        atomicAdd(&deg[dst[b * 256 + threadIdx.x]], 1);
    } else {
        atomicAdd(&bcnt[bid[(b - E_EDGES / 256) * 256 + threadIdx.x]], 1);
    }
}

// ================= fused scans + bprime =================
__global__ __launch_bounds__(256) void scan_all(
    const int* __restrict__ deg, int* __restrict__ offs,
    const int* __restrict__ bcnt, int* __restrict__ boffs,
    const float* __restrict__ bim, const float* __restrict__ Wap,
    const float* __restrict__ bap, float* __restrict__ bp)
{
    const int t = threadIdx.x;
    if (blockIdx.x == 0) {
        __shared__ int s[257];
        const int base = t * 48;
        int sum = 0;
        for (int j = 0; j < 48; ++j) sum += deg[base + j];
        s[t] = sum;
        __syncthreads();
        if (t == 0) {
            int acc = 0;
            for (int i = 0; i < 256; ++i) { int v = s[i]; s[i] = acc; acc += v; }
            s[256] = acc;
        }
        __syncthreads();
        int run = s[t];
        for (int j = 0; j < 48; ++j) { offs[base + j] = run; run += deg[base + j]; }
        if (t == 255) offs[N_NODES] = s[256];
    } else if (blockIdx.x == 1) {
        if (t == 0) {
            int acc = 0;
            for (int i = 0; i < B_EX; ++i) { boffs[i] = acc; acc += bcnt[i]; }
            boffs[B_EX] = acc;
        }
    } else {
        int n = (blockIdx.x - 2) * 256 + t;
        float s = bap[n];
        for (int k = 0; k < DD_OUT; ++k) s += bim[k] * Wap[(size_t)k * DD_OUT + n];
        bp[n] = s;
    }
}

// ================= fused scatter (edges + nodes) =================
__global__ __launch_bounds__(256) void scatter_all(
    const int* __restrict__ src, const int* __restrict__ dst,
    const int* __restrict__ offs, int* __restrict__ cur, int* __restrict__ ssrc,
    const int* __restrict__ bid, const int* __restrict__ boffs,
    int* __restrict__ bcur, int* __restrict__ nlist)
{
    int b = blockIdx.x;
    if (b < E_EDGES / 256) {
        int i = b * 256 + threadIdx.x;
        int d = dst[i];
        int p = offs[d] + atomicAdd(&cur[d], 1);
        ssrc[p] = src[i];
    } else {
        int i = (b - E_EDGES / 256) * 256 + threadIdx.x;
        int e = bid[i];
        int p = boffs[e] + atomicAdd(&bcur[e], 1);
        nlist[p] = i;
    }
}

// ================= attention logits + softmax =================
__global__ __launch_bounds__(128, 4) void att_kernel(
    const float* __restrict__ node_proj_s, const float* __restrict__ img_proj,
    const int* __restrict__ batch_ids, const float* __restrict__ Wa,
    float* __restrict__ att)
{
    __shared__ float red[2][R_REG][68];
    const int wv = threadIdx.x >> 6;
    const int n = blockIdx.x * 2 + wv;
    const int lane = threadIdx.x & 63;
    const int b = batch_ids[n];

    const float4 nps = *(const float4*)(node_proj_s + (size_t)n * P_DIM + 4 * lane);
    const float4 wa = *(const float4*)(Wa + 4 * lane);
    const float* ip0 = img_proj + (size_t)b * R_REG * P_DIM + 4 * lane;

#pragma unroll
    for (int r = 0; r < R_REG; ++r) {
        float4 ip = *(const float4*)(ip0 + (size_t)r * P_DIM);
        float t0 = fexp2(fmaf(ip.x, TANH_C, nps.x));
        float t1 = fexp2(fmaf(ip.y, TANH_C, nps.y));
        float t2 = fexp2(fmaf(ip.z, TANH_C, nps.z));
        float t3 = fexp2(fmaf(ip.w, TANH_C, nps.w));
        float p;
        p = wa.x * frcp(t0 + 1.f);
        p = fmaf(wa.y, frcp(t1 + 1.f), p);
        p = fmaf(wa.z, frcp(t2 + 1.f), p);
        p = fmaf(wa.w, frcp(t3 + 1.f), p);
        red[wv][r][lane] = p;
    }
    __syncthreads();

    float logit = -INFINITY;
    if (lane < R_REG) {
        const float* row = &red[wv][lane][0];
        float4 s4 = *(const float4*)row;
#pragma unroll
        for (int c = 4; c < 64; c += 4) {
            float4 v = *(const float4*)(row + c);
            s4.x += v.x; s4.y += v.y; s4.z += v.z; s4.w += v.w;
        }
        logit = -2.f * ((s4.x + s4.y) + (s4.z + s4.w));
    }
    float m = logit;
#pragma unroll
    for (int off = 32; off; off >>= 1) m = fmaxf(m, __shfl_xor(m, off));
    float e = (lane < R_REG) ? __expf(logit - m) : 0.f;
    float s = e;
#pragma unroll
    for (int off = 32; off; off >>= 1) s += __shfl_xor(s, off);
    if (lane < R_REG) att[(size_t)n * R_REG + lane] = e / s;
}

// ======= batched attended Z-feature: imgz[n] = sum_r att[n][r] * Z[b][r] (512c f32) ====
#define IA_SLICES 16
__global__ __launch_bounds__(256) void img_att_batched(
    const float* __restrict__ att, const ushort* __restrict__ Z,
    const int* __restrict__ boffs, const int* __restrict__ nlist,
    float* __restrict__ imgz)
{
    const int b     = blockIdx.x & 63;
    const int slice = blockIdx.x >> 6;
    const int t = threadIdx.x;
    const int c0 = 2 * t;

    const int ns = boffs[b], ne = boffs[b + 1];
    const int cnt = ne - ns;
    const int per = (cnt + IA_SLICES - 1) / IA_SLICES;
    const int i0 = ns + slice * per;
    const int i1 = min(i0 + per, ne);
    if (i0 >= i1) return;

    float2 col[R_REG];
    const ushort* base = Z + (size_t)b * R_REG * DD_OUT + c0;
#pragma unroll
    for (int r = 0; r < R_REG; ++r) {
        ushort2 u = *(const ushort2*)(base + (size_t)r * DD_OUT);
        col[r].x = bf2f(u.x); col[r].y = bf2f(u.y);
    }

    __shared__ float att_s[8][R_REG];
    for (int i = i0; i < i1; i += 8) {
        int g = min(8, i1 - i);
        __syncthreads();
        for (int idx = t; idx < g * R_REG; idx += 256) {
            int j = idx / R_REG, r = idx - j * R_REG;
            att_s[j][r] = att[(size_t)nlist[i + j] * R_REG + r];
        }
        __syncthreads();
        for (int j = 0; j < g; ++j) {
            float4 av[9];
#pragma unroll
            for (int q = 0; q < 9; ++q) av[q] = *(const float4*)&att_s[j][q * 4];
            float ax = 0.f, ay = 0.f;
#pragma unroll
            for (int r = 0; r < R_REG; ++r) {
                float a = (r & 2) ? ((r & 1) ? av[r >> 2].w : av[r >> 2].z)
                                  : ((r & 1) ? av[r >> 2].y : av[r >> 2].x);
                ax += a * col[r].x;
                ay += a * col[r].y;
            }
            float2 o; o.x = ax; o.y = ay;
            *(float2*)&imgz[(size_t)nlist[i + j] * DD_OUT + c0] = o;
        }
    }
}

// ================= CSR gather: wave per node, lane = 8 cols (uint4), unroll x2 ====
__device__ __forceinline__ void acc8(float* a, uint4 v) {
    a[0] += bf2f((ushort)(v.x & 0xffffu)); a[1] += bf2f((ushort)(v.x >> 16));
    a[2] += bf2f((ushort)(v.y & 0xffffu)); a[3] += bf2f((ushort)(v.y >> 16));
    a[4] += bf2f((ushort)(v.z & 0xffffu)); a[5] += bf2f((ushort)(v.z >> 16));
    a[6] += bf2f((ushort)(v.w & 0xffffu)); a[7] += bf2f((ushort)(v.w >> 16));
}

__global__ __launch_bounds__(256) void gather_neigh(
    const int* __restrict__ off, const int* __restrict__ ssrc,
    const ushort* __restrict__ A2h1 /* A2 + H1_OFF */,
    ushort* __restrict__ A2nb /* A2 + NEIGH_OFF */)
{
    const int wv = threadIdx.x >> 6;
    const int n = blockIdx.x * 4 + wv;
    const int lane = threadIdx.x & 63;
    const int e0 = off[n], e1 = off[n + 1];

    float a[8] = {};
    int e = e0;
    for (; e + 2 <= e1; e += 2) {
        int s0 = ssrc[e], s1 = ssrc[e + 1];
        uint4 v0 = *(const uint4*)(A2h1 + (size_t)s0 * A2_LD + lane * 8);
        uint4 v1 = *(const uint4*)(A2h1 + (size_t)s1 * A2_LD + lane * 8);
        acc8(a, v0);
        acc8(a, v1);
    }
    if (e < e1) {
        int s0 = ssrc[e];
        uint4 v0 = *(const uint4*)(A2h1 + (size_t)s0 * A2_LD + lane * 8);
        acc8(a, v0);
    }
    ushort8v o;
#pragma unroll
    for (int i = 0; i < 8; ++i) o[i] = f2bf(a[i]);
    *(ushort8v*)(A2nb + (size_t)n * A2_LD + lane * 8) = o;
}

extern "C" void kernel_launch(void* const* d_in, const int* in_sizes, int n_in,
                              void* d_out, int out_size, void* d_ws, size_t ws_size,
                              hipStream_t stream) {
    const float* h         = (const float*)d_in[0];
    const float* img_feats = (const float*)d_in[1];
    const int*   batch_ids = (const int*)d_in[2];
    const int*   src       = (const int*)d_in[3];
    const int*   dst       = (const int*)d_in[4];
    const float* Wf  = (const float*)d_in[5];
    const float* bf  = (const float*)d_in[6];
    const float* Wi  = (const float*)d_in[7];
    const float* bi  = (const float*)d_in[8];
    const float* Wa  = (const float*)d_in[9];
    // d_in[10] = ba: constant logit shift, cancels in softmax
    const float* Wn  = (const float*)d_in[11];
    const float* bn  = (const float*)d_in[12];
    const float* Wim = (const float*)d_in[13];
    const float* bim = (const float*)d_in[14];
    const float* Wap = (const float*)d_in[15];
    const float* bap = (const float*)d_in[16];
    float* out = (float*)d_out;
    float* ws  = (float*)d_ws;

    // ---- workspace layout (offsets in 4-byte words) ----
    ushort* A2      = (ushort*)(ws + 0);          // [12288][1024] bf16: neigh|h1
    float*  imgz    = ws + 6291456;               // [12288][512] f32
    float*  node_proj = ws + 12582912;            // [12288][256] f32 pre-scaled
    float*  img_proj  = ws + 15728640;            // [2304][256]  f32
    float*  att       = ws + 16318464;            // [12288][36]  f32
    ushort* Z      = (ushort*)(ws + 16760832);    // [2304][512] bf16
    ushort* WfnT   = (ushort*)(ws + 17350656);    // [768][512] bf16
    ushort* WiZT   = (ushort*)(ws + 17547264);    // [768][1024] bf16: Wi^T | W'^T
    ushort* Wap1T  = (ushort*)(ws + 17940480);    // [512][512] bf16
    ushort* BT2    = (ushort*)(ws + 18071552);    // [512][1024] bf16: Wap1^T | Wap2^T
    float*  bprime = ws + 18333696;               // [512]
    // zeroed region (contiguous): deg, cur, bcnt, bcur
    int* deg  = (int*)(ws + 18334208);            // [12288]
    int* cur  = deg + N_NODES;                    // [12288]
    int* bcnt = cur + N_NODES;                    // [64]
    int* bcur = bcnt + B_EX;                      // [64]
    int* offs = bcur + B_EX;                      // [12289]
    int* boffs = offs + N_NODES + 1;              // [65]
    int* ssrc = boffs + B_EX + 1;                 // [196608]
    int* nlist = ssrc + E_EDGES;                  // [12288]

    dim3 blk(256);

    // ---- preamble: weight transposes + zero counters ----
    preamble<<<dim3(TR_BLKS + ZERO_BLKS), blk, 0, stream>>>(
        Wf, Wn, Wi, Wap, WfnT, WiZT, Wap1T, BT2, deg);

    // ---- CSR build + batch sort ----
    count_all<<<dim3(E_EDGES / 256 + N_NODES / 256), blk, 0, stream>>>(dst, batch_ids, deg, bcnt);
    scan_all<<<dim3(4), blk, 0, stream>>>(deg, offs, bcnt, boffs, bim, Wap, bap, bprime);
    scatter_all<<<dim3(E_EDGES / 256 + N_NODES / 256), blk, 0, stream>>>(
        src, dst, offs, cur, ssrc, batch_ids, boffs, bcur, nlist);

    // ---- W'^T = Wap1^T @ Wim^T -> WiZT rows 256..767 ----
    gemm_wp<<<dim3(8, 4), blk, 0, stream>>>(Wap1T, Wim, WiZT);
    // ---- [img_proj | Z] = img_feats @ [Wi | W'] ----
    gemm_imgz<<<dim3(6, 18), blk, 0, stream>>>(img_feats, WiZT, bi, img_proj, Z);
    // ---- fused: node_proj_s (scaled) + h1 -> A2 h1 cols ----
    gemm_fused_first<<<dim3(6, 96), blk, 0, stream>>>(h, WfnT, bf, bn, node_proj, A2);
    // ---- attention ----
    att_kernel<<<dim3(N_NODES / 2), dim3(128), 0, stream>>>(node_proj, img_proj, batch_ids, Wa, att);
    img_att_batched<<<dim3(B_EX * IA_SLICES), blk, 0, stream>>>(att, Z, boffs, nlist, imgz);
    // ---- neigh = segment_sum(h1[src], dst) -> A2 neigh cols ----
    gather_neigh<<<dim3(N_NODES / 4), blk, 0, stream>>>(offs, ssrc, A2 + H1_OFF, A2 + NEIGH_OFF);
    // ---- out = relu(A2 @ [Wap1; Wap2] + imgz + b') ----
    gemm_out<<<dim3(8, 96), blk, 0, stream>>>(A2, BT2, bprime, imgz, out);
}

// Round 11
// 240.519 us; speedup vs baseline: 1.0666x; 1.0383x over previous
//
#include <hip/hip_runtime.h>
#include <cstdint>
#include <cstddef>

#define N_NODES 12288
#define B_EX    64
#define R_REG   36
#define E_EDGES 196608
#define DD_IN   512
#define DD_OUT  512
#define P_DIM   256
#define D_IMG   1024
#define TANH_C  2.885390081777927f   // 2*log2(e)

// A2 concatenated GEMM operand: [12288][1024] bf16 : neigh | h1
#define A2_LD     1024
#define NEIGH_OFF 0
#define H1_OFF    512

typedef unsigned short ushort;
typedef __bf16 bf16x8 __attribute__((ext_vector_type(8)));
typedef float f32x4 __attribute__((ext_vector_type(4)));
typedef ushort ushort4v __attribute__((ext_vector_type(4)));
typedef ushort ushort8v __attribute__((ext_vector_type(8)));

__device__ __forceinline__ ushort f2bf(float f) {
    uint32_t u = __float_as_uint(f);
    uint32_t r = (u + 0x7fffu + ((u >> 16) & 1u)) >> 16;
    return (ushort)r;
}
__device__ __forceinline__ float bf2f(ushort u) {
    return __uint_as_float(((uint32_t)u) << 16);
}
__device__ __forceinline__ void gload_lds16(const void* g, void* l) {
    __builtin_amdgcn_global_load_lds((const __attribute__((address_space(1))) void*)g,
                                     (__attribute__((address_space(3))) void*)l, 16, 0, 0);
}
// reg-staged f32 -> bf16 LDS fill (used only in small/latency-tolerant GEMMs)
__device__ __forceinline__ void stage_f32(const float* __restrict__ src, void* ldsDst) {
    float4 v0 = *(const float4*)src;
    float4 v1 = *(const float4*)(src + 4);
    ushort8v o;
    o[0] = f2bf(v0.x); o[1] = f2bf(v0.y); o[2] = f2bf(v0.z); o[3] = f2bf(v0.w);
    o[4] = f2bf(v1.x); o[5] = f2bf(v1.y); o[6] = f2bf(v1.z); o[7] = f2bf(v1.w);
    *(ushort8v*)ldsDst = o;
}
__device__ __forceinline__ float fexp2(float x) {
    float r; asm("v_exp_f32 %0, %1" : "=v"(r) : "v"(x)); return r;
}
__device__ __forceinline__ float frcp(float x) {
    float r; asm("v_rcp_f32 %0, %1" : "=v"(r) : "v"(x)); return r;
}
// bijective XCD swizzle for nwg % 8 == 0 (identity otherwise)
__device__ __forceinline__ int xcd_swz(int lin, int nwg) {
    if ((nwg & 7) == 0) return (lin & 7) * (nwg >> 3) + (lin >> 3);
    return lin;
}

// ========== gemm_wp: W'^T = Wap1T @ Wim^T -> WiZT rows 256..767 ==========
// A = Wap1T [512][512] bf16 (gload), BT = Wim f32 [1024][512] (reg-staged). grid (8,4).
__global__ __launch_bounds__(256) void gemm_wp(
    const ushort* __restrict__ A, const float* __restrict__ BTf,
    ushort* __restrict__ WiZT)
{
    __shared__ ushort As[128 * 64];
    __shared__ ushort Bs[128 * 64];
    const int K = DD_IN;
    const int tid = threadIdx.x;
    const int lane = tid & 63;
    const int wid = tid >> 6;
    const int wm = wid >> 1, wn = wid & 1;
    const int lin = blockIdx.y * 8 + blockIdx.x;
    const int m0 = (lin >> 3) * 128, n0 = (lin & 7) * 128;

    f32x4 acc[4][4] = {};
    const int srow = tid >> 3;
    const int schk = tid & 7;
    const char* AsB = (const char*)As;
    const char* BsB = (const char*)Bs;

    for (int k0 = 0; k0 < K; k0 += 64) {
#pragma unroll
        for (int i = 0; i < 4; ++i) {
            int row = i * 32 + srow;
            int ca = (schk ^ (row & 7)) * 8;
            gload_lds16(A + (size_t)(m0 + row) * K + k0 + ca,
                        (char*)As + i * 4096 + wid * 1024);
            stage_f32(BTf + (size_t)(n0 + row) * K + k0 + ca,
                      (char*)Bs + i * 4096 + wid * 1024 + lane * 16);
        }
        __syncthreads();
#pragma unroll
        for (int kk = 0; kk < 2; ++kk) {
            const int kc = kk * 4 + (lane >> 4);
            bf16x8 af[4], bfr[4];
#pragma unroll
            for (int i = 0; i < 4; ++i) {
                int row = wm * 64 + i * 16 + (lane & 15);
                af[i] = *(const bf16x8*)(AsB + row * 128 + ((kc ^ (row & 7)) << 4));
            }
#pragma unroll
            for (int j = 0; j < 4; ++j) {
                int col = wn * 64 + j * 16 + (lane & 15);
                bfr[j] = *(const bf16x8*)(BsB + col * 128 + ((kc ^ (col & 7)) << 4));
            }
#pragma unroll
            for (int i = 0; i < 4; ++i)
#pragma unroll
                for (int j = 0; j < 4; ++j)
                    acc[i][j] = __builtin_amdgcn_mfma_f32_16x16x32_bf16(af[i], bfr[j], acc[i][j], 0, 0, 0);
        }
        __syncthreads();
    }

#pragma unroll
    for (int i = 0; i < 4; ++i)
#pragma unroll
        for (int j = 0; j < 4; ++j)
#pragma unroll
            for (int q = 0; q < 4; ++q) {
                int row = m0 + wm * 64 + i * 16 + (lane >> 4) * 4 + q;   // W' col 0..511
                int col = n0 + wn * 64 + j * 16 + (lane & 15);           // W' row 0..1023
                WiZT[(size_t)(256 + row) * D_IMG + col] = f2bf(acc[i][j][q]);
            }
}

// ========== gemm_imgz: A = img_feats f32 [2304][1024] (reg-staged), BT = WiZT [768][1024]
// cols 0..255  -> img_proj f32 (+bi); cols 256..767 -> Z bf16 [2304][512]. grid (6,18).
__global__ __launch_bounds__(256) void gemm_imgz(
    const float* __restrict__ Af, const ushort* __restrict__ BT,
    const float* __restrict__ bi, float* __restrict__ img_proj,
    ushort* __restrict__ Z)
{
    __shared__ ushort As[128 * 64];
    __shared__ ushort Bs[128 * 64];
    const int K = D_IMG;
    const int tid = threadIdx.x;
    const int lane = tid & 63;
    const int wid = tid >> 6;
    const int wm = wid >> 1, wn = wid & 1;
    const int lin = blockIdx.y * 6 + blockIdx.x;
    const int m0 = (lin / 6) * 128, n0 = (lin % 6) * 128;

    f32x4 acc[4][4] = {};
    const int srow = tid >> 3;
    const int schk = tid & 7;
    const char* AsB = (const char*)As;
    const char* BsB = (const char*)Bs;

    for (int k0 = 0; k0 < K; k0 += 64) {
#pragma unroll
        for (int i = 0; i < 4; ++i) {
            int row = i * 32 + srow;
            int ca = (schk ^ (row & 7)) * 8;
            stage_f32(Af + (size_t)(m0 + row) * K + k0 + ca,
                      (char*)As + i * 4096 + wid * 1024 + lane * 16);
            gload_lds16(BT + (size_t)(n0 + row) * K + k0 + ca,
                        (char*)Bs + i * 4096 + wid * 1024);
        }
        __syncthreads();
#pragma unroll
        for (int kk = 0; kk < 2; ++kk) {
            const int kc = kk * 4 + (lane >> 4);
            bf16x8 af[4], bfr[4];
#pragma unroll
            for (int i = 0; i < 4; ++i) {
                int row = wm * 64 + i * 16 + (lane & 15);
                af[i] = *(const bf16x8*)(AsB + row * 128 + ((kc ^ (row & 7)) << 4));
            }
#pragma unroll
            for (int j = 0; j < 4; ++j) {
                int col = wn * 64 + j * 16 + (lane & 15);
                bfr[j] = *(const bf16x8*)(BsB + col * 128 + ((kc ^ (col & 7)) << 4));
            }
#pragma unroll
            for (int i = 0; i < 4; ++i)
#pragma unroll
                for (int j = 0; j < 4; ++j)
                    acc[i][j] = __builtin_amdgcn_mfma_f32_16x16x32_bf16(af[i], bfr[j], acc[i][j], 0, 0, 0);
        }
        __syncthreads();
    }

    if (n0 < 256) {
#pragma unroll
        for (int i = 0; i < 4; ++i)
#pragma unroll
            for (int j = 0; j < 4; ++j)
#pragma unroll
                for (int q = 0; q < 4; ++q) {
                    int row = m0 + wm * 64 + i * 16 + (lane >> 4) * 4 + q;
                    int col = n0 + wn * 64 + j * 16 + (lane & 15);
                    img_proj[(size_t)row * P_DIM + col] = acc[i][j][q] + bi[col];
                }
    } else {
#pragma unroll
        for (int i = 0; i < 4; ++i)
#pragma unroll
            for (int j = 0; j < 4; ++j)
#pragma unroll
                for (int q = 0; q < 4; ++q) {
                    int row = m0 + wm * 64 + i * 16 + (lane >> 4) * 4 + q;
                    int col = n0 - 256 + wn * 64 + j * 16 + (lane & 15);
                    Z[(size_t)row * DD_OUT + col] = f2bf(acc[i][j][q]);
                }
    }
}

// ========== fused first GEMM: A = h_bf [12288][512] bf16 (gload_lds), BT=[WfT;WnT] ====
// BM=128, BN=64, grid (12, 96) = 1152 blocks = 4.5/CU. acc[2][4], LDS 24 KB.
// cols 0..255 -> node_proj_s = (acc+bf)*TANH_C f32; cols 256..767 -> A2 h1 bf16.
__global__ __launch_bounds__(256) void gemm_fused_first(
    const ushort* __restrict__ A, const ushort* __restrict__ BT,
    const float* __restrict__ biasF, const float* __restrict__ biasN,
    float* __restrict__ node_proj_s, ushort* __restrict__ A2)
{
    __shared__ ushort As[128 * 64];
    __shared__ ushort Bs[64 * 64];
    const int K = DD_IN;
    const int tid = threadIdx.x;
    const int lane = tid & 63;
    const int wid = tid >> 6;
    const int lin = xcd_swz(blockIdx.y * 12 + blockIdx.x, 1152);
    const int m0 = (lin / 12) * 128, n0 = (lin % 12) * 64;

    f32x4 acc[2][4] = {};
    const int srow = tid >> 3;
    const int schk = tid & 7;
    const char* AsB = (const char*)As;
    const char* BsB = (const char*)Bs;

    for (int k0 = 0; k0 < K; k0 += 64) {
#pragma unroll
        for (int i = 0; i < 4; ++i) {
            int row = i * 32 + srow;
            int ca = (schk ^ (row & 7)) * 8;
            gload_lds16(A + (size_t)(m0 + row) * K + k0 + ca,
                        (char*)As + i * 4096 + wid * 1024);
        }
#pragma unroll
        for (int i = 0; i < 2; ++i) {
            int row = i * 32 + srow;
            int cb = (schk ^ (row & 7)) * 8;
            gload_lds16(BT + (size_t)(n0 + row) * K + k0 + cb,
                        (char*)Bs + i * 4096 + wid * 1024);
        }
        __syncthreads();
#pragma unroll
        for (int kk = 0; kk < 2; ++kk) {
            const int kc = kk * 4 + (lane >> 4);
            bf16x8 af[2], bfr[4];
#pragma unroll
            for (int i = 0; i < 2; ++i) {
                int row = wid * 32 + i * 16 + (lane & 15);
                af[i] = *(const bf16x8*)(AsB + row * 128 + ((kc ^ (row & 7)) << 4));
            }
#pragma unroll
            for (int j = 0; j < 4; ++j) {
                int col = j * 16 + (lane & 15);
                bfr[j] = *(const bf16x8*)(BsB + col * 128 + ((kc ^ (col & 7)) << 4));
            }
#pragma unroll
            for (int i = 0; i < 2; ++i)
#pragma unroll
                for (int j = 0; j < 4; ++j)
                    acc[i][j] = __builtin_amdgcn_mfma_f32_16x16x32_bf16(af[i], bfr[j], acc[i][j], 0, 0, 0);
        }
        __syncthreads();
    }

    if (n0 < 256) {
#pragma unroll
        for (int i = 0; i < 2; ++i)
#pragma unroll
            for (int j = 0; j < 4; ++j)
#pragma unroll
                for (int q = 0; q < 4; ++q) {
                    int row = m0 + wid * 32 + i * 16 + (lane >> 4) * 4 + q;
                    int col = n0 + j * 16 + (lane & 15);
                    node_proj_s[(size_t)row * P_DIM + col] = (acc[i][j][q] + biasF[col]) * TANH_C;
                }
    } else {
#pragma unroll
        for (int i = 0; i < 2; ++i)
#pragma unroll
            for (int j = 0; j < 4; ++j)
#pragma unroll
                for (int q = 0; q < 4; ++q) {
                    int row = m0 + wid * 32 + i * 16 + (lane >> 4) * 4 + q;
                    int col = n0 - 256 + j * 16 + (lane & 15);
                    A2[(size_t)row * A2_LD + H1_OFF + col] = f2bf(acc[i][j][q] + biasN[col]);
                }
    }
}

// ========== final GEMM: out = relu(A2 @ BT2^T + imgz + b'), BM=128 BN=64, K=1024 ====
__global__ __launch_bounds__(256) void gemm_out(
    const ushort* __restrict__ A, const ushort* __restrict__ BT,
    const float* __restrict__ bias, const float* __restrict__ Cadd,
    float* __restrict__ Cf)
{
    __shared__ ushort As[128 * 64];
    __shared__ ushort Bs[64 * 64];
    const int K = A2_LD;
    const int tid = threadIdx.x;
    const int lane = tid & 63;
    const int wid = tid >> 6;
    const int lin = xcd_swz(blockIdx.y * 8 + blockIdx.x, 768);
    const int m0 = (lin >> 3) * 128, n0 = (lin & 7) * 64;

    f32x4 acc[2][4] = {};
    const int srow = tid >> 3;
    const int schk = tid & 7;
    const char* AsB = (const char*)As;
    const char* BsB = (const char*)Bs;

    for (int k0 = 0; k0 < K; k0 += 64) {
#pragma unroll
        for (int i = 0; i < 4; ++i) {
            int row = i * 32 + srow;
            int ca = (schk ^ (row & 7)) * 8;
            gload_lds16(A + (size_t)(m0 + row) * K + k0 + ca,
                        (char*)As + i * 4096 + wid * 1024);
        }
#pragma unroll
        for (int i = 0; i < 2; ++i) {
            int row = i * 32 + srow;
            int cb = (schk ^ (row & 7)) * 8;
            gload_lds16(BT + (size_t)(n0 + row) * K + k0 + cb,
                        (char*)Bs + i * 4096 + wid * 1024);
        }
        __syncthreads();
#pragma unroll
        for (int kk = 0; kk < 2; ++kk) {
            const int kc = kk * 4 + (lane >> 4);
            bf16x8 af[2], bfr[4];
#pragma unroll
            for (int i = 0; i < 2; ++i) {
                int row = wid * 32 + i * 16 + (lane & 15);
                af[i] = *(const bf16x8*)(AsB + row * 128 + ((kc ^ (row & 7)) << 4));
            }
#pragma unroll
            for (int j = 0; j < 4; ++j) {
                int col = j * 16 + (lane & 15);
                bfr[j] = *(const bf16x8*)(BsB + col * 128 + ((kc ^ (col & 7)) << 4));
            }
#pragma unroll
            for (int i = 0; i < 2; ++i)
#pragma unroll
                for (int j = 0; j < 4; ++j)
                    acc[i][j] = __builtin_amdgcn_mfma_f32_16x16x32_bf16(af[i], bfr[j], acc[i][j], 0, 0, 0);
        }
        __syncthreads();
    }

#pragma unroll
    for (int i = 0; i < 2; ++i)
#pragma unroll
        for (int j = 0; j < 4; ++j)
#pragma unroll
            for (int q = 0; q < 4; ++q) {
                int row = m0 + wid * 32 + i * 16 + (lane >> 4) * 4 + q;
                int col = n0 + j * 16 + (lane & 15);
                float v = acc[i][j][q] + bias[col] + Cadd[(size_t)row * DD_OUT + col];
                Cf[(size_t)row * DD_OUT + col] = fmaxf(v, 0.f);
            }
}

// ======== preamble: h cvt + weight transposes + counter zero ========
#define PCVT_BLKS (N_NODES * DD_IN / 4 / 256)   // 6144
#define TR_BLKS   352
#define ZERO_INTS (2 * N_NODES + 2 * B_EX)      // 24704
#define ZERO_BLKS ((ZERO_INTS + 255) / 256)     // 97
__global__ __launch_bounds__(256) void preamble(
    const float* __restrict__ h, ushort* __restrict__ h_bf,
    const float* __restrict__ Wf, const float* __restrict__ Wn,
    const float* __restrict__ Wi, const float* __restrict__ Wap,
    ushort* __restrict__ WfnT, ushort* __restrict__ WiZT,
    ushort* __restrict__ Wap1T, ushort* __restrict__ BT2,
    int* __restrict__ zero_p)
{
    if (blockIdx.x < PCVT_BLKS) {
        int i = blockIdx.x * 256 + threadIdx.x;
        float4 v = ((const float4*)h)[i];
        ushort4v o;
        o[0] = f2bf(v.x); o[1] = f2bf(v.y); o[2] = f2bf(v.z); o[3] = f2bf(v.w);
        ((ushort4v*)h_bf)[i] = o;
        return;
    }
    if (blockIdx.x >= PCVT_BLKS + TR_BLKS) {
        int i = (blockIdx.x - PCVT_BLKS - TR_BLKS) * 256 + threadIdx.x;
        if (i < ZERO_INTS) zero_p[i] = 0;
        return;
    }
    int t = blockIdx.x - PCVT_BLKS;
    const float* W; ushort* WT; int N, ldt, gx;
    if (t < 32)       { W = Wf;  WT = WfnT;                        N = 256; ldt = 512;  gx = 4; }
    else if (t < 96)  { W = Wn;  WT = WfnT + 256 * 512;            N = 512; ldt = 512;  gx = 8; t -= 32; }
    else if (t < 160) { W = Wi;  WT = WiZT;                        N = 256; ldt = 1024; gx = 4; t -= 96; }
    else if (t < 224) { W = Wap; WT = Wap1T;                       N = 512; ldt = 512;  gx = 8; t -= 160; }
    else if (t < 288) { W = Wap; WT = BT2 + NEIGH_OFF;             N = 512; ldt = 1024; gx = 8; t -= 224; }
    else              { W = Wap + 512 * 512; WT = BT2 + H1_OFF;    N = 512; ldt = 1024; gx = 8; t -= 288; }
    const int n0 = (t % gx) * 64, k0 = (t / gx) * 64;

    __shared__ float tt[64][65];
    const int tx = threadIdx.x & 15, ty = threadIdx.x >> 4;
#pragma unroll
    for (int r = 0; r < 4; ++r) {
        float4 v = *(const float4*)&W[(size_t)(k0 + ty * 4 + r) * N + n0 + tx * 4];
        tt[ty * 4 + r][tx * 4 + 0] = v.x;
        tt[ty * 4 + r][tx * 4 + 1] = v.y;
        tt[ty * 4 + r][tx * 4 + 2] = v.z;
        tt[ty * 4 + r][tx * 4 + 3] = v.w;
    }
    __syncthreads();
    const int nl = threadIdx.x >> 2, kq = (threadIdx.x & 3) * 16;
    ushort u[16] __attribute__((aligned(16)));
#pragma unroll
    for (int c = 0; c < 16; ++c) u[c] = f2bf(tt[kq + c][nl]);
    ushort* d = &WT[(size_t)(n0 + nl) * ldt + k0 + kq];
    *(ushort8v*)d = *(ushort8v*)&u[0];
    *(ushort8v*)(d + 8) = *(ushort8v*)&u[8];
}

// ================= fused counting (edges by dst + nodes by batch) =================
__global__ __launch_bounds__(256) void count_all(
    const int* __restrict__ dst, const int* __restrict__ bid,
    int* __restrict__ deg, int* __restrict__ bcnt)
{
    int b = blockIdx.x;
    if (b < E_EDGES / 256) {
        atomicAdd(&deg[dst[b * 256 + threadIdx.x]], 1);
    } else {
        atomicAdd(&bcnt[bid[(b - E_EDGES / 256) * 256 + threadIdx.x]], 1);
    }
}

// ================= fused scans + bprime =================
__global__ __launch_bounds__(256) void scan_all(
    const int* __restrict__ deg, int* __restrict__ offs,
    const int* __restrict__ bcnt, int* __restrict__ boffs,
    const float* __restrict__ bim, const float* __restrict__ Wap,
    const float* __restrict__ bap, float* __restrict__ bp)
{
    const int t = threadIdx.x;
    if (blockIdx.x == 0) {
        __shared__ int s[257];
        const int base = t * 48;
        int sum = 0;
        for (int j = 0; j < 48; ++j) sum += deg[base + j];
        s[t] = sum;
        __syncthreads();
        if (t == 0) {
            int acc = 0;
            for (int i = 0; i < 256; ++i) { int v = s[i]; s[i] = acc; acc += v; }
            s[256] = acc;
        }
        __syncthreads();
        int run = s[t];
        for (int j = 0; j < 48; ++j) { offs[base + j] = run; run += deg[base + j]; }
        if (t == 255) offs[N_NODES] = s[256];
    } else if (blockIdx.x == 1) {
        if (t == 0) {
            int acc = 0;
            for (int i = 0; i < B_EX; ++i) { boffs[i] = acc; acc += bcnt[i]; }
            boffs[B_EX] = acc;
        }
    } else {
        int n = (blockIdx.x - 2) * 256 + t;
        float s = bap[n];
        for (int k = 0; k < DD_OUT; ++k) s += bim[k] * Wap[(size_t)k * DD_OUT + n];
        bp[n] = s;
    }
}

// ================= fused scatter (edges + nodes) =================
__global__ __launch_bounds__(256) void scatter_all(
    const int* __restrict__ src, const int* __restrict__ dst,
    const int* __restrict__ offs, int* __restrict__ cur, int* __restrict__ ssrc,
    const int* __restrict__ bid, const int* __restrict__ boffs,
    int* __restrict__ bcur, int* __restrict__ nlist)
{
    int b = blockIdx.x;
    if (b < E_EDGES / 256) {
        int i = b * 256 + threadIdx.x;
        int d = dst[i];
        int p = offs[d] + atomicAdd(&cur[d], 1);
        ssrc[p] = src[i];
    } else {
        int i = (b - E_EDGES / 256) * 256 + threadIdx.x;
        int e = bid[i];
        int p = boffs[e] + atomicAdd(&bcur[e], 1);
        nlist[p] = i;
    }
}

// ================= attention logits + softmax =================
__global__ __launch_bounds__(128, 4) void att_kernel(
    const float* __restrict__ node_proj_s, const float* __restrict__ img_proj,
    const int* __restrict__ batch_ids, const float* __restrict__ Wa,
    float* __restrict__ att)
{
    __shared__ float red[2][R_REG][68];
    const int wv = threadIdx.x >> 6;
    const int n = blockIdx.x * 2 + wv;
    const int lane = threadIdx.x & 63;
    const int b = batch_ids[n];

    const float4 nps = *(const float4*)(node_proj_s + (size_t)n * P_DIM + 4 * lane);
    const float4 wa = *(const float4*)(Wa + 4 * lane);
    const float* ip0 = img_proj + (size_t)b * R_REG * P_DIM + 4 * lane;

#pragma unroll
    for (int r = 0; r < R_REG; ++r) {
        float4 ip = *(const float4*)(ip0 + (size_t)r * P_DIM);
        float t0 = fexp2(fmaf(ip.x, TANH_C, nps.x));
        float t1 = fexp2(fmaf(ip.y, TANH_C, nps.y));
        float t2 = fexp2(fmaf(ip.z, TANH_C, nps.z));
        float t3 = fexp2(fmaf(ip.w, TANH_C, nps.w));
        float p;
        p = wa.x * frcp(t0 + 1.f);
        p = fmaf(wa.y, frcp(t1 + 1.f), p);
        p = fmaf(wa.z, frcp(t2 + 1.f), p);
        p = fmaf(wa.w, frcp(t3 + 1.f), p);
        red[wv][r][lane] = p;
    }
    __syncthreads();

    float logit = -INFINITY;
    if (lane < R_REG) {
        const float* row = &red[wv][lane][0];
        float4 s4 = *(const float4*)row;
#pragma unroll
        for (int c = 4; c < 64; c += 4) {
            float4 v = *(const float4*)(row + c);
            s4.x += v.x; s4.y += v.y; s4.z += v.z; s4.w += v.w;
        }
        logit = -2.f * ((s4.x + s4.y) + (s4.z + s4.w));
    }
    float m = logit;
#pragma unroll
    for (int off = 32; off; off >>= 1) m = fmaxf(m, __shfl_xor(m, off));
    float e = (lane < R_REG) ? __expf(logit - m) : 0.f;
    float s = e;
#pragma unroll
    for (int off = 32; off; off >>= 1) s += __shfl_xor(s, off);
    if (lane < R_REG) att[(size_t)n * R_REG + lane] = e / s;
}

// ======= batched attended Z-feature: imgz[n] = sum_r att[n][r] * Z[b][r] (512c f32) ====
#define IA_SLICES 16
__global__ __launch_bounds__(256) void img_att_batched(
    const float* __restrict__ att, const ushort* __restrict__ Z,
    const int* __restrict__ boffs, const int* __restrict__ nlist,
    float* __restrict__ imgz)
{
    const int b     = blockIdx.x & 63;
    const int slice = blockIdx.x >> 6;
    const int t = threadIdx.x;
    const int c0 = 2 * t;

    const int ns = boffs[b], ne = boffs[b + 1];
    const int cnt = ne - ns;
    const int per = (cnt + IA_SLICES - 1) / IA_SLICES;
    const int i0 = ns + slice * per;
    const int i1 = min(i0 + per, ne);
    if (i0 >= i1) return;

    float2 col[R_REG];
    const ushort* base = Z + (size_t)b * R_REG * DD_OUT + c0;
#pragma unroll
    for (int r = 0; r < R_REG; ++r) {
        ushort2 u = *(const ushort2*)(base + (size_t)r * DD_OUT);
        col[r].x = bf2f(u.x); col[r].y = bf2f(u.y);
    }

    __shared__ float att_s[8][R_REG];
    for (int i = i0; i < i1; i += 8) {
        int g = min(8, i1 - i);
        __syncthreads();
        for (int idx = t; idx < g * R_REG; idx += 256) {
            int j = idx / R_REG, r = idx - j * R_REG;
            att_s[j][r] = att[(size_t)nlist[i + j] * R_REG + r];
        }
        __syncthreads();
        for (int j = 0; j < g; ++j) {
            float4 av[9];
#pragma unroll
            for (int q = 0; q < 9; ++q) av[q] = *(const float4*)&att_s[j][q * 4];
            float ax = 0.f, ay = 0.f;
#pragma unroll
            for (int r = 0; r < R_REG; ++r) {
                float a = (r & 2) ? ((r & 1) ? av[r >> 2].w : av[r >> 2].z)
                                  : ((r & 1) ? av[r >> 2].y : av[r >> 2].x);
                ax += a * col[r].x;
                ay += a * col[r].y;
            }
            float2 o; o.x = ax; o.y = ay;
            *(float2*)&imgz[(size_t)nlist[i + j] * DD_OUT + c0] = o;
        }
    }
}

// ================= CSR gather: wave per node, lane = 8 cols (uint4), unroll x2 ====
__device__ __forceinline__ void acc8(float* a, uint4 v) {
    a[0] += bf2f((ushort)(v.x & 0xffffu)); a[1] += bf2f((ushort)(v.x >> 16));
    a[2] += bf2f((ushort)(v.y & 0xffffu)); a[3] += bf2f((ushort)(v.y >> 16));
    a[4] += bf2f((ushort)(v.z & 0xffffu)); a[5] += bf2f((ushort)(v.z >> 16));
    a[6] += bf2f((ushort)(v.w & 0xffffu)); a[7] += bf2f((ushort)(v.w >> 16));
}

__global__ __launch_bounds__(256) void gather_neigh(
    const int* __restrict__ off, const int* __restrict__ ssrc,
    const ushort* __restrict__ A2h1 /* A2 + H1_OFF */,
    ushort* __restrict__ A2nb /* A2 + NEIGH_OFF */)
{
    const int wv = threadIdx.x >> 6;
    const int n = blockIdx.x * 4 + wv;
    const int lane = threadIdx.x & 63;
    const int e0 = off[n], e1 = off[n + 1];

    float a[8] = {};
    int e = e0;
    for (; e + 2 <= e1; e += 2) {
        int s0 = ssrc[e], s1 = ssrc[e + 1];
        uint4 v0 = *(const uint4*)(A2h1 + (size_t)s0 * A2_LD + lane * 8);
        uint4 v1 = *(const uint4*)(A2h1 + (size_t)s1 * A2_LD + lane * 8);
        acc8(a, v0);
        acc8(a, v1);
    }
    if (e < e1) {
        int s0 = ssrc[e];
        uint4 v0 = *(const uint4*)(A2h1 + (size_t)s0 * A2_LD + lane * 8);
        acc8(a, v0);
    }
    ushort8v o;
#pragma unroll
    for (int i = 0; i < 8; ++i) o[i] = f2bf(a[i]);
    *(ushort8v*)(A2nb + (size_t)n * A2_LD + lane * 8) = o;
}

extern "C" void kernel_launch(void* const* d_in, const int* in_sizes, int n_in,
                              void* d_out, int out_size, void* d_ws, size_t ws_size,
                              hipStream_t stream) {
    const float* h         = (const float*)d_in[0];
    const float* img_feats = (const float*)d_in[1];
    const int*   batch_ids = (const int*)d_in[2];
    const int*   src       = (const int*)d_in[3];
    const int*   dst       = (const int*)d_in[4];
    const float* Wf  = (const float*)d_in[5];
    const float* bf  = (const float*)d_in[6];
    const float* Wi  = (const float*)d_in[7];
    const float* bi  = (const float*)d_in[8];
    const float* Wa  = (const float*)d_in[9];
    // d_in[10] = ba: constant logit shift, cancels in softmax
    const float* Wn  = (const float*)d_in[11];
    const float* bn  = (const float*)d_in[12];
    const float* Wim = (const float*)d_in[13];
    const float* bim = (const float*)d_in[14];
    const float* Wap = (const float*)d_in[15];
    const float* bap = (const float*)d_in[16];
    float* out = (float*)d_out;
    float* ws  = (float*)d_ws;

    // ---- workspace layout (offsets in 4-byte words) ----
    ushort* A2      = (ushort*)(ws + 0);          // [12288][1024] bf16: neigh|h1
    float*  imgz    = ws + 6291456;               // [12288][512] f32
    float*  node_proj = ws + 12582912;            // [12288][256] f32 pre-scaled
    float*  img_proj  = ws + 15728640;            // [2304][256]  f32
    float*  att       = ws + 16318464;            // [12288][36]  f32
    ushort* Z      = (ushort*)(ws + 16760832);    // [2304][512] bf16
    ushort* h_bf   = (ushort*)(ws + 17350656);    // [12288][512] bf16
    ushort* WfnT   = (ushort*)(ws + 20496384);    // [768][512] bf16
    ushort* WiZT   = (ushort*)(ws + 20692992);    // [768][1024] bf16: Wi^T | W'^T
    ushort* Wap1T  = (ushort*)(ws + 21086208);    // [512][512] bf16
    ushort* BT2    = (ushort*)(ws + 21217280);    // [512][1024] bf16: Wap1^T | Wap2^T
    float*  bprime = ws + 21479424;               // [512]
    // zeroed region (contiguous): deg, cur, bcnt, bcur
    int* deg  = (int*)(ws + 21479936);            // [12288]
    int* cur  = deg + N_NODES;                    // [12288]
    int* bcnt = cur + N_NODES;                    // [64]
    int* bcur = bcnt + B_EX;                      // [64]
    int* offs = bcur + B_EX;                      // [12289]
    int* boffs = offs + N_NODES + 1;              // [65]
    int* ssrc = boffs + B_EX + 1;                 // [196608]
    int* nlist = ssrc + E_EDGES;                  // [12288]

    dim3 blk(256);

    // ---- preamble: h cvt + weight transposes + zero counters ----
    preamble<<<dim3(PCVT_BLKS + TR_BLKS + ZERO_BLKS), blk, 0, stream>>>(
        h, h_bf, Wf, Wn, Wi, Wap, WfnT, WiZT, Wap1T, BT2, deg);

    // ---- CSR build + batch sort ----
    count_all<<<dim3(E_EDGES / 256 + N_NODES / 256), blk, 0, stream>>>(dst, batch_ids, deg, bcnt);
    scan_all<<<dim3(4), blk, 0, stream>>>(deg, offs, bcnt, boffs, bim, Wap, bap, bprime);
    scatter_all<<<dim3(E_EDGES / 256 + N_NODES / 256), blk, 0, stream>>>(
        src, dst, offs, cur, ssrc, batch_ids, boffs, bcur, nlist);

    // ---- W'^T = Wap1^T @ Wim^T -> WiZT rows 256..767 ----
    gemm_wp<<<dim3(8, 4), blk, 0, stream>>>(Wap1T, Wim, WiZT);
    // ---- [img_proj | Z] = img_feats @ [Wi | W'] ----
    gemm_imgz<<<dim3(6, 18), blk, 0, stream>>>(img_feats, WiZT, bi, img_proj, Z);
    // ---- fused: node_proj_s (scaled) + h1 -> A2 h1 cols ----
    gemm_fused_first<<<dim3(12, 96), blk, 0, stream>>>(h_bf, WfnT, bf, bn, node_proj, A2);
    // ---- attention ----
    att_kernel<<<dim3(N_NODES / 2), dim3(128), 0, stream>>>(node_proj, img_proj, batch_ids, Wa, att);
    img_att_batched<<<dim3(B_EX * IA_SLICES), blk, 0, stream>>>(att, Z, boffs, nlist, imgz);
    // ---- neigh = segment_sum(h1[src], dst) -> A2 neigh cols ----
    gather_neigh<<<dim3(N_NODES / 4), blk, 0, stream>>>(offs, ssrc, A2 + H1_OFF, A2 + NEIGH_OFF);
    // ---- out = relu(A2 @ [Wap1; Wap2] + imgz + b') ----
    gemm_out<<<dim3(8, 96), blk, 0, stream>>>(A2, BT2, bprime, imgz, out);
}

// Round 12
// 213.452 us; speedup vs baseline: 1.2018x; 1.1268x over previous
//
#include <hip/hip_runtime.h>
#include <cstdint>
#include <cstddef>

#define N_NODES 12288
#define B_EX    64
#define R_REG   36
#define E_EDGES 196608
#define DD_IN   512
#define DD_OUT  512
#define P_DIM   256
#define D_IMG   1024
#define TANH_C  2.885390081777927f   // 2*log2(e)

// A2 concatenated GEMM operand: [12288][1024] bf16 : neigh | h1
#define A2_LD     1024
#define NEIGH_OFF 0
#define H1_OFF    512

typedef unsigned short ushort;
typedef __bf16 bf16x8 __attribute__((ext_vector_type(8)));
typedef float f32x4 __attribute__((ext_vector_type(4)));
typedef ushort ushort4v __attribute__((ext_vector_type(4)));
typedef ushort ushort8v __attribute__((ext_vector_type(8)));

__device__ __forceinline__ ushort f2bf(float f) {
    uint32_t u = __float_as_uint(f);
    uint32_t r = (u + 0x7fffu + ((u >> 16) & 1u)) >> 16;
    return (ushort)r;
}
__device__ __forceinline__ float bf2f(ushort u) {
    return __uint_as_float(((uint32_t)u) << 16);
}
__device__ __forceinline__ void gload_lds16(const void* g, void* l) {
    __builtin_amdgcn_global_load_lds((const __attribute__((address_space(1))) void*)g,
                                     (__attribute__((address_space(3))) void*)l, 16, 0, 0);
}
// reg-staged f32 -> bf16 LDS fill (used only in small/latency-tolerant GEMMs)
__device__ __forceinline__ void stage_f32(const float* __restrict__ src, void* ldsDst) {
    float4 v0 = *(const float4*)src;
    float4 v1 = *(const float4*)(src + 4);
    ushort8v o;
    o[0] = f2bf(v0.x); o[1] = f2bf(v0.y); o[2] = f2bf(v0.z); o[3] = f2bf(v0.w);
    o[4] = f2bf(v1.x); o[5] = f2bf(v1.y); o[6] = f2bf(v1.z); o[7] = f2bf(v1.w);
    *(ushort8v*)ldsDst = o;
}
__device__ __forceinline__ float fexp2(float x) {
    float r; asm("v_exp_f32 %0, %1" : "=v"(r) : "v"(x)); return r;
}
__device__ __forceinline__ float frcp(float x) {
    float r; asm("v_rcp_f32 %0, %1" : "=v"(r) : "v"(x)); return r;
}
// bijective XCD swizzle for nwg % 8 == 0 (identity otherwise)
__device__ __forceinline__ int xcd_swz(int lin, int nwg) {
    if ((nwg & 7) == 0) return (lin & 7) * (nwg >> 3) + (lin >> 3);
    return lin;
}

// ======== k1 preamble: h cvt + weight transposes + counter zero ========
#define PCVT_BLKS (N_NODES * DD_IN / 4 / 256)   // 6144
#define TR_BLKS   352
#define ZERO_INTS (2 * N_NODES + 2 * B_EX)      // 24704
#define ZERO_BLKS ((ZERO_INTS + 255) / 256)     // 97
__global__ __launch_bounds__(256) void preamble(
    const float* __restrict__ h, ushort* __restrict__ h_bf,
    const float* __restrict__ Wf, const float* __restrict__ Wn,
    const float* __restrict__ Wi, const float* __restrict__ Wap,
    ushort* __restrict__ WfnT, ushort* __restrict__ WiZT,
    ushort* __restrict__ Wap1T, ushort* __restrict__ BT2,
    int* __restrict__ zero_p)
{
    if (blockIdx.x < PCVT_BLKS) {
        int i = blockIdx.x * 256 + threadIdx.x;
        float4 v = ((const float4*)h)[i];
        ushort4v o;
        o[0] = f2bf(v.x); o[1] = f2bf(v.y); o[2] = f2bf(v.z); o[3] = f2bf(v.w);
        ((ushort4v*)h_bf)[i] = o;
        return;
    }
    if (blockIdx.x >= PCVT_BLKS + TR_BLKS) {
        int i = (blockIdx.x - PCVT_BLKS - TR_BLKS) * 256 + threadIdx.x;
        if (i < ZERO_INTS) zero_p[i] = 0;
        return;
    }
    int t = blockIdx.x - PCVT_BLKS;
    const float* W; ushort* WT; int N, ldt, gx;
    if (t < 32)       { W = Wf;  WT = WfnT;                        N = 256; ldt = 512;  gx = 4; }
    else if (t < 96)  { W = Wn;  WT = WfnT + 256 * 512;            N = 512; ldt = 512;  gx = 8; t -= 32; }
    else if (t < 160) { W = Wi;  WT = WiZT;                        N = 256; ldt = 1024; gx = 4; t -= 96; }
    else if (t < 224) { W = Wap; WT = Wap1T;                       N = 512; ldt = 512;  gx = 8; t -= 160; }
    else if (t < 288) { W = Wap; WT = BT2 + NEIGH_OFF;             N = 512; ldt = 1024; gx = 8; t -= 224; }
    else              { W = Wap + 512 * 512; WT = BT2 + H1_OFF;    N = 512; ldt = 1024; gx = 8; t -= 288; }
    const int n0 = (t % gx) * 64, k0 = (t / gx) * 64;

    __shared__ float tt[64][65];
    const int tx = threadIdx.x & 15, ty = threadIdx.x >> 4;
#pragma unroll
    for (int r = 0; r < 4; ++r) {
        float4 v = *(const float4*)&W[(size_t)(k0 + ty * 4 + r) * N + n0 + tx * 4];
        tt[ty * 4 + r][tx * 4 + 0] = v.x;
        tt[ty * 4 + r][tx * 4 + 1] = v.y;
        tt[ty * 4 + r][tx * 4 + 2] = v.z;
        tt[ty * 4 + r][tx * 4 + 3] = v.w;
    }
    __syncthreads();
    const int nl = threadIdx.x >> 2, kq = (threadIdx.x & 3) * 16;
    ushort u[16] __attribute__((aligned(16)));
#pragma unroll
    for (int c = 0; c < 16; ++c) u[c] = f2bf(tt[kq + c][nl]);
    ushort* d = &WT[(size_t)(n0 + nl) * ldt + k0 + kq];
    *(ushort8v*)d = *(ushort8v*)&u[0];
    *(ushort8v*)(d + 8) = *(ushort8v*)&u[8];
}

// ======== k2: count_all (blocks 0..815) || gemm_wp (blocks 816..847) ========
// count: edges by dst + nodes by batch. wp: W'^T = Wap1T @ Wim^T -> WiZT rows 256..767.
#define CNT_BLKS (E_EDGES / 256 + N_NODES / 256)   // 816
__global__ __launch_bounds__(256) void k2_count_wp(
    const int* __restrict__ dst, const int* __restrict__ bid,
    int* __restrict__ deg, int* __restrict__ bcnt,
    const ushort* __restrict__ Wap1T, const float* __restrict__ Wim,
    ushort* __restrict__ WiZT)
{
    __shared__ ushort As[128 * 64];
    __shared__ ushort Bs[128 * 64];
    if (blockIdx.x < CNT_BLKS) {
        int b = blockIdx.x;
        if (b < E_EDGES / 256) {
            atomicAdd(&deg[dst[b * 256 + threadIdx.x]], 1);
        } else {
            atomicAdd(&bcnt[bid[(b - E_EDGES / 256) * 256 + threadIdx.x]], 1);
        }
        return;
    }
    const int K = DD_IN;
    const int tid = threadIdx.x;
    const int lane = tid & 63;
    const int wid = tid >> 6;
    const int wm = wid >> 1, wn = wid & 1;
    const int lin = blockIdx.x - CNT_BLKS;
    const int m0 = (lin >> 3) * 128, n0 = (lin & 7) * 128;

    f32x4 acc[4][4] = {};
    const int srow = tid >> 3;
    const int schk = tid & 7;
    const char* AsB = (const char*)As;
    const char* BsB = (const char*)Bs;

    for (int k0 = 0; k0 < K; k0 += 64) {
#pragma unroll
        for (int i = 0; i < 4; ++i) {
            int row = i * 32 + srow;
            int ca = (schk ^ (row & 7)) * 8;
            gload_lds16(Wap1T + (size_t)(m0 + row) * K + k0 + ca,
                        (char*)As + i * 4096 + wid * 1024);
            stage_f32(Wim + (size_t)(n0 + row) * K + k0 + ca,
                      (char*)Bs + i * 4096 + wid * 1024 + lane * 16);
        }
        __syncthreads();
#pragma unroll
        for (int kk = 0; kk < 2; ++kk) {
            const int kc = kk * 4 + (lane >> 4);
            bf16x8 af[4], bfr[4];
#pragma unroll
            for (int i = 0; i < 4; ++i) {
                int row = wm * 64 + i * 16 + (lane & 15);
                af[i] = *(const bf16x8*)(AsB + row * 128 + ((kc ^ (row & 7)) << 4));
            }
#pragma unroll
            for (int j = 0; j < 4; ++j) {
                int col = wn * 64 + j * 16 + (lane & 15);
                bfr[j] = *(const bf16x8*)(BsB + col * 128 + ((kc ^ (col & 7)) << 4));
            }
#pragma unroll
            for (int i = 0; i < 4; ++i)
#pragma unroll
                for (int j = 0; j < 4; ++j)
                    acc[i][j] = __builtin_amdgcn_mfma_f32_16x16x32_bf16(af[i], bfr[j], acc[i][j], 0, 0, 0);
        }
        __syncthreads();
    }

#pragma unroll
    for (int i = 0; i < 4; ++i)
#pragma unroll
        for (int j = 0; j < 4; ++j)
#pragma unroll
            for (int q = 0; q < 4; ++q) {
                int row = m0 + wm * 64 + i * 16 + (lane >> 4) * 4 + q;   // W' col
                int col = n0 + wn * 64 + j * 16 + (lane & 15);           // W' row
                WiZT[(size_t)(256 + row) * D_IMG + col] = f2bf(acc[i][j][q]);
            }
}

// ======== k3: scan_all+bprime (blocks 0..3) || gemm_imgz (blocks 4..111) ========
__global__ __launch_bounds__(256) void k3_scan_imgz(
    const int* __restrict__ deg, int* __restrict__ offs,
    const int* __restrict__ bcnt, int* __restrict__ boffs,
    const float* __restrict__ bim, const float* __restrict__ Wap,
    const float* __restrict__ bap, float* __restrict__ bp,
    const float* __restrict__ imgf, const ushort* __restrict__ WiZT,
    const float* __restrict__ bi, float* __restrict__ img_proj,
    ushort* __restrict__ Z)
{
    __shared__ ushort As[128 * 64];
    __shared__ ushort Bs[128 * 64];
    const int t = threadIdx.x;
    if (blockIdx.x < 4) {
        if (blockIdx.x == 0) {
            __shared__ int s[257];
            const int base = t * 48;
            int sum = 0;
            for (int j = 0; j < 48; ++j) sum += deg[base + j];
            s[t] = sum;
            __syncthreads();
            if (t == 0) {
                int acc = 0;
                for (int i = 0; i < 256; ++i) { int v = s[i]; s[i] = acc; acc += v; }
                s[256] = acc;
            }
            __syncthreads();
            int run = s[t];
            for (int j = 0; j < 48; ++j) { offs[base + j] = run; run += deg[base + j]; }
            if (t == 255) offs[N_NODES] = s[256];
        } else if (blockIdx.x == 1) {
            if (t == 0) {
                int acc = 0;
                for (int i = 0; i < B_EX; ++i) { boffs[i] = acc; acc += bcnt[i]; }
                boffs[B_EX] = acc;
            }
        } else {
            int n = (blockIdx.x - 2) * 256 + t;
            float s = bap[n];
            for (int k = 0; k < DD_OUT; ++k) s += bim[k] * Wap[(size_t)k * DD_OUT + n];
            bp[n] = s;
        }
        return;
    }
    // ---- imgz GEMM: [img_proj | Z] = img_feats @ [Wi | W'] ----
    const int K = D_IMG;
    const int lane = t & 63;
    const int wid = t >> 6;
    const int wm = wid >> 1, wn = wid & 1;
    const int lin = blockIdx.x - 4;
    const int m0 = (lin / 6) * 128, n0 = (lin % 6) * 128;

    f32x4 acc[4][4] = {};
    const int srow = t >> 3;
    const int schk = t & 7;
    const char* AsB = (const char*)As;
    const char* BsB = (const char*)Bs;

    for (int k0 = 0; k0 < K; k0 += 64) {
#pragma unroll
        for (int i = 0; i < 4; ++i) {
            int row = i * 32 + srow;
            int ca = (schk ^ (row & 7)) * 8;
            stage_f32(imgf + (size_t)(m0 + row) * K + k0 + ca,
                      (char*)As + i * 4096 + wid * 1024 + lane * 16);
            gload_lds16(WiZT + (size_t)(n0 + row) * K + k0 + ca,
                        (char*)Bs + i * 4096 + wid * 1024);
        }
        __syncthreads();
#pragma unroll
        for (int kk = 0; kk < 2; ++kk) {
            const int kc = kk * 4 + (lane >> 4);
            bf16x8 af[4], bfr[4];
#pragma unroll
            for (int i = 0; i < 4; ++i) {
                int row = wm * 64 + i * 16 + (lane & 15);
                af[i] = *(const bf16x8*)(AsB + row * 128 + ((kc ^ (row & 7)) << 4));
            }
#pragma unroll
            for (int j = 0; j < 4; ++j) {
                int col = wn * 64 + j * 16 + (lane & 15);
                bfr[j] = *(const bf16x8*)(BsB + col * 128 + ((kc ^ (col & 7)) << 4));
            }
#pragma unroll
            for (int i = 0; i < 4; ++i)
#pragma unroll
                for (int j = 0; j < 4; ++j)
                    acc[i][j] = __builtin_amdgcn_mfma_f32_16x16x32_bf16(af[i], bfr[j], acc[i][j], 0, 0, 0);
        }
        __syncthreads();
    }

    if (n0 < 256) {
#pragma unroll
        for (int i = 0; i < 4; ++i)
#pragma unroll
            for (int j = 0; j < 4; ++j)
#pragma unroll
                for (int q = 0; q < 4; ++q) {
                    int row = m0 + wm * 64 + i * 16 + (lane >> 4) * 4 + q;
                    int col = n0 + wn * 64 + j * 16 + (lane & 15);
                    img_proj[(size_t)row * P_DIM + col] = acc[i][j][q] + bi[col];
                }
    } else {
#pragma unroll
        for (int i = 0; i < 4; ++i)
#pragma unroll
            for (int j = 0; j < 4; ++j)
#pragma unroll
                for (int q = 0; q < 4; ++q) {
                    int row = m0 + wm * 64 + i * 16 + (lane >> 4) * 4 + q;
                    int col = n0 - 256 + wn * 64 + j * 16 + (lane & 15);
                    Z[(size_t)row * DD_OUT + col] = f2bf(acc[i][j][q]);
                }
    }
}

// ======== k4: scatter_all (blocks 0..815) || gemm_fused_first (816..1967) ========
__global__ __launch_bounds__(256) void k4_scatter_ff(
    const int* __restrict__ src, const int* __restrict__ dst,
    const int* __restrict__ offs, int* __restrict__ cur, int* __restrict__ ssrc,
    const int* __restrict__ bid, const int* __restrict__ boffs,
    int* __restrict__ bcur, int* __restrict__ nlist,
    const ushort* __restrict__ h_bf, const ushort* __restrict__ WfnT,
    const float* __restrict__ biasF, const float* __restrict__ biasN,
    float* __restrict__ node_proj_s, ushort* __restrict__ A2)
{
    __shared__ ushort As[128 * 64];
    __shared__ ushort Bs[64 * 64];
    if (blockIdx.x < CNT_BLKS) {
        int b = blockIdx.x;
        if (b < E_EDGES / 256) {
            int i = b * 256 + threadIdx.x;
            int d = dst[i];
            int p = offs[d] + atomicAdd(&cur[d], 1);
            ssrc[p] = src[i];
        } else {
            int i = (b - E_EDGES / 256) * 256 + threadIdx.x;
            int e = bid[i];
            int p = boffs[e] + atomicAdd(&bcur[e], 1);
            nlist[p] = i;
        }
        return;
    }
    // ---- fused first GEMM: BM=128, BN=64, 1152 blocks ----
    const int K = DD_IN;
    const int tid = threadIdx.x;
    const int lane = tid & 63;
    const int wid = tid >> 6;
    const int lin = xcd_swz(blockIdx.x - CNT_BLKS, 1152);
    const int m0 = (lin / 12) * 128, n0 = (lin % 12) * 64;

    f32x4 acc[2][4] = {};
    const int srow = tid >> 3;
    const int schk = tid & 7;
    const char* AsB = (const char*)As;
    const char* BsB = (const char*)Bs;

    for (int k0 = 0; k0 < K; k0 += 64) {
#pragma unroll
        for (int i = 0; i < 4; ++i) {
            int row = i * 32 + srow;
            int ca = (schk ^ (row & 7)) * 8;
            gload_lds16(h_bf + (size_t)(m0 + row) * K + k0 + ca,
                        (char*)As + i * 4096 + wid * 1024);
        }
#pragma unroll
        for (int i = 0; i < 2; ++i) {
            int row = i * 32 + srow;
            int cb = (schk ^ (row & 7)) * 8;
            gload_lds16(WfnT + (size_t)(n0 + row) * K + k0 + cb,
                        (char*)Bs + i * 4096 + wid * 1024);
        }
        __syncthreads();
#pragma unroll
        for (int kk = 0; kk < 2; ++kk) {
            const int kc = kk * 4 + (lane >> 4);
            bf16x8 af[2], bfr[4];
#pragma unroll
            for (int i = 0; i < 2; ++i) {
                int row = wid * 32 + i * 16 + (lane & 15);
                af[i] = *(const bf16x8*)(AsB + row * 128 + ((kc ^ (row & 7)) << 4));
            }
#pragma unroll
            for (int j = 0; j < 4; ++j) {
                int col = j * 16 + (lane & 15);
                bfr[j] = *(const bf16x8*)(BsB + col * 128 + ((kc ^ (col & 7)) << 4));
            }
#pragma unroll
            for (int i = 0; i < 2; ++i)
#pragma unroll
                for (int j = 0; j < 4; ++j)
                    acc[i][j] = __builtin_amdgcn_mfma_f32_16x16x32_bf16(af[i], bfr[j], acc[i][j], 0, 0, 0);
        }
        __syncthreads();
    }

    if (n0 < 256) {
#pragma unroll
        for (int i = 0; i < 2; ++i)
#pragma unroll
            for (int j = 0; j < 4; ++j)
#pragma unroll
                for (int q = 0; q < 4; ++q) {
                    int row = m0 + wid * 32 + i * 16 + (lane >> 4) * 4 + q;
                    int col = n0 + j * 16 + (lane & 15);
                    node_proj_s[(size_t)row * P_DIM + col] = (acc[i][j][q] + biasF[col]) * TANH_C;
                }
    } else {
#pragma unroll
        for (int i = 0; i < 2; ++i)
#pragma unroll
            for (int j = 0; j < 4; ++j)
#pragma unroll
                for (int q = 0; q < 4; ++q) {
                    int row = m0 + wid * 32 + i * 16 + (lane >> 4) * 4 + q;
                    int col = n0 - 256 + j * 16 + (lane & 15);
                    A2[(size_t)row * A2_LD + H1_OFF + col] = f2bf(acc[i][j][q] + biasN[col]);
                }
    }
}

// ======== k5: att_kernel (blocks 0..3071, 4 nodes/block) || gather_neigh (3072..6143) ====
__device__ __forceinline__ void acc8(float* a, uint4 v) {
    a[0] += bf2f((ushort)(v.x & 0xffffu)); a[1] += bf2f((ushort)(v.x >> 16));
    a[2] += bf2f((ushort)(v.y & 0xffffu)); a[3] += bf2f((ushort)(v.y >> 16));
    a[4] += bf2f((ushort)(v.z & 0xffffu)); a[5] += bf2f((ushort)(v.z >> 16));
    a[6] += bf2f((ushort)(v.w & 0xffffu)); a[7] += bf2f((ushort)(v.w >> 16));
}

__global__ __launch_bounds__(256) void k5_att_gather(
    const float* __restrict__ node_proj_s, const float* __restrict__ img_proj,
    const int* __restrict__ batch_ids, const float* __restrict__ Wa,
    float* __restrict__ att,
    const int* __restrict__ off, const int* __restrict__ ssrc,
    const ushort* __restrict__ A2h1, ushort* __restrict__ A2nb)
{
    __shared__ float red[4][R_REG][68];
    const int lane = threadIdx.x & 63;
    const int wv = threadIdx.x >> 6;
    if (blockIdx.x < N_NODES / 4) {
        const int n = blockIdx.x * 4 + wv;
        const int b = batch_ids[n];

        const float4 nps = *(const float4*)(node_proj_s + (size_t)n * P_DIM + 4 * lane);
        const float4 wa = *(const float4*)(Wa + 4 * lane);
        const float* ip0 = img_proj + (size_t)b * R_REG * P_DIM + 4 * lane;

#pragma unroll
        for (int r = 0; r < R_REG; ++r) {
            float4 ip = *(const float4*)(ip0 + (size_t)r * P_DIM);
            float t0 = fexp2(fmaf(ip.x, TANH_C, nps.x));
            float t1 = fexp2(fmaf(ip.y, TANH_C, nps.y));
            float t2 = fexp2(fmaf(ip.z, TANH_C, nps.z));
            float t3 = fexp2(fmaf(ip.w, TANH_C, nps.w));
            float p;
            p = wa.x * frcp(t0 + 1.f);
            p = fmaf(wa.y, frcp(t1 + 1.f), p);
            p = fmaf(wa.z, frcp(t2 + 1.f), p);
            p = fmaf(wa.w, frcp(t3 + 1.f), p);
            red[wv][r][lane] = p;
        }
        __syncthreads();

        float logit = -INFINITY;
        if (lane < R_REG) {
            const float* row = &red[wv][lane][0];
            float4 s4 = *(const float4*)row;
#pragma unroll
            for (int c = 4; c < 64; c += 4) {
                float4 v = *(const float4*)(row + c);
                s4.x += v.x; s4.y += v.y; s4.z += v.z; s4.w += v.w;
            }
            logit = -2.f * ((s4.x + s4.y) + (s4.z + s4.w));
        }
        float m = logit;
#pragma unroll
        for (int o = 32; o; o >>= 1) m = fmaxf(m, __shfl_xor(m, o));
        float e = (lane < R_REG) ? __expf(logit - m) : 0.f;
        float s = e;
#pragma unroll
        for (int o = 32; o; o >>= 1) s += __shfl_xor(s, o);
        if (lane < R_REG) att[(size_t)n * R_REG + lane] = e / s;
        return;
    }
    // ---- gather: wave per node, lane = 8 cols (uint4), unroll x2 ----
    const int n = (blockIdx.x - N_NODES / 4) * 4 + wv;
    const int e0 = off[n], e1 = off[n + 1];

    float a[8] = {};
    int e = e0;
    for (; e + 2 <= e1; e += 2) {
        int s0 = ssrc[e], s1 = ssrc[e + 1];
        uint4 v0 = *(const uint4*)(A2h1 + (size_t)s0 * A2_LD + lane * 8);
        uint4 v1 = *(const uint4*)(A2h1 + (size_t)s1 * A2_LD + lane * 8);
        acc8(a, v0);
        acc8(a, v1);
    }
    if (e < e1) {
        int s0 = ssrc[e];
        uint4 v0 = *(const uint4*)(A2h1 + (size_t)s0 * A2_LD + lane * 8);
        acc8(a, v0);
    }
    ushort8v o;
#pragma unroll
    for (int i = 0; i < 8; ++i) o[i] = f2bf(a[i]);
    *(ushort8v*)(A2nb + (size_t)n * A2_LD + lane * 8) = o;
}

// ======= k6: batched attended Z-feature: imgz[n] = sum_r att[n][r]*Z[b][r] (bf16 out) ====
#define IA_SLICES 16
__global__ __launch_bounds__(256) void img_att_batched(
    const float* __restrict__ att, const ushort* __restrict__ Z,
    const int* __restrict__ boffs, const int* __restrict__ nlist,
    ushort* __restrict__ imgz)
{
    const int b     = blockIdx.x & 63;
    const int slice = blockIdx.x >> 6;
    const int t = threadIdx.x;
    const int c0 = 2 * t;

    const int ns = boffs[b], ne = boffs[b + 1];
    const int cnt = ne - ns;
    const int per = (cnt + IA_SLICES - 1) / IA_SLICES;
    const int i0 = ns + slice * per;
    const int i1 = min(i0 + per, ne);
    if (i0 >= i1) return;

    float2 col[R_REG];
    const ushort* base = Z + (size_t)b * R_REG * DD_OUT + c0;
#pragma unroll
    for (int r = 0; r < R_REG; ++r) {
        ushort2 u = *(const ushort2*)(base + (size_t)r * DD_OUT);
        col[r].x = bf2f(u.x); col[r].y = bf2f(u.y);
    }

    __shared__ float att_s[8][R_REG];
    for (int i = i0; i < i1; i += 8) {
        int g = min(8, i1 - i);
        __syncthreads();
        for (int idx = t; idx < g * R_REG; idx += 256) {
            int j = idx / R_REG, r = idx - j * R_REG;
            att_s[j][r] = att[(size_t)nlist[i + j] * R_REG + r];
        }
        __syncthreads();
        for (int j = 0; j < g; ++j) {
            float4 av[9];
#pragma unroll
            for (int q = 0; q < 9; ++q) av[q] = *(const float4*)&att_s[j][q * 4];
            float ax = 0.f, ay = 0.f;
#pragma unroll
            for (int r = 0; r < R_REG; ++r) {
                float a = (r & 2) ? ((r & 1) ? av[r >> 2].w : av[r >> 2].z)
                                  : ((r & 1) ? av[r >> 2].y : av[r >> 2].x);
                ax += a * col[r].x;
                ay += a * col[r].y;
            }
            ushort2 o; o.x = f2bf(ax); o.y = f2bf(ay);
            *(ushort2*)&imgz[(size_t)nlist[i + j] * DD_OUT + c0] = o;
        }
    }
}

// ======== k7: final GEMM: out = relu(A2 @ BT2^T + imgz + b'), BM=128 BN=64, K=1024 ====
__global__ __launch_bounds__(256) void gemm_out(
    const ushort* __restrict__ A, const ushort* __restrict__ BT,
    const float* __restrict__ bias, const ushort* __restrict__ Cadd,
    float* __restrict__ Cf)
{
    __shared__ ushort As[128 * 64];
    __shared__ ushort Bs[64 * 64];
    const int K = A2_LD;
    const int tid = threadIdx.x;
    const int lane = tid & 63;
    const int wid = tid >> 6;
    const int lin = xcd_swz(blockIdx.y * 8 + blockIdx.x, 768);
    const int m0 = (lin >> 3) * 128, n0 = (lin & 7) * 64;

    f32x4 acc[2][4] = {};
    const int srow = tid >> 3;
    const int schk = tid & 7;
    const char* AsB = (const char*)As;
    const char* BsB = (const char*)Bs;

    for (int k0 = 0; k0 < K; k0 += 64) {
#pragma unroll
        for (int i = 0; i < 4; ++i) {
            int row = i * 32 + srow;
            int ca = (schk ^ (row & 7)) * 8;
            gload_lds16(A + (size_t)(m0 + row) * K + k0 + ca,
                        (char*)As + i * 4096 + wid * 1024);
        }
#pragma unroll
        for (int i = 0; i < 2; ++i) {
            int row = i * 32 + srow;
            int cb = (schk ^ (row & 7)) * 8;
            gload_lds16(BT + (size_t)(n0 + row) * K + k0 + cb,
                        (char*)Bs + i * 4096 + wid * 1024);
        }
        __syncthreads();
#pragma unroll
        for (int kk = 0; kk < 2; ++kk) {
            const int kc = kk * 4 + (lane >> 4);
            bf16x8 af[2], bfr[4];
#pragma unroll
            for (int i = 0; i < 2; ++i) {
                int row = wid * 32 + i * 16 + (lane & 15);
                af[i] = *(const bf16x8*)(AsB + row * 128 + ((kc ^ (row & 7)) << 4));
            }
#pragma unroll
            for (int j = 0; j < 4; ++j) {
                int col = j * 16 + (lane & 15);
                bfr[j] = *(const bf16x8*)(BsB + col * 128 + ((kc ^ (col & 7)) << 4));
            }
#pragma unroll
            for (int i = 0; i < 2; ++i)
#pragma unroll
                for (int j = 0; j < 4; ++j)
                    acc[i][j] = __builtin_amdgcn_mfma_f32_16x16x32_bf16(af[i], bfr[j], acc[i][j], 0, 0, 0);
        }
        __syncthreads();
    }

#pragma unroll
    for (int i = 0; i < 2; ++i)
#pragma unroll
        for (int j = 0; j < 4; ++j)
#pragma unroll
            for (int q = 0; q < 4; ++q) {
                int row = m0 + wid * 32 + i * 16 + (lane >> 4) * 4 + q;
                int col = n0 + j * 16 + (lane & 15);
                float v = acc[i][j][q] + bias[col] + bf2f(Cadd[(size_t)row * DD_OUT + col]);
                Cf[(size_t)row * DD_OUT + col] = fmaxf(v, 0.f);
            }
}

extern "C" void kernel_launch(void* const* d_in, const int* in_sizes, int n_in,
                              void* d_out, int out_size, void* d_ws, size_t ws_size,
                              hipStream_t stream) {
    const float* h         = (const float*)d_in[0];
    const float* img_feats = (const float*)d_in[1];
    const int*   batch_ids = (const int*)d_in[2];
    const int*   src       = (const int*)d_in[3];
    const int*   dst       = (const int*)d_in[4];
    const float* Wf  = (const float*)d_in[5];
    const float* bf  = (const float*)d_in[6];
    const float* Wi  = (const float*)d_in[7];
    const float* bi  = (const float*)d_in[8];
    const float* Wa  = (const float*)d_in[9];
    // d_in[10] = ba: constant logit shift, cancels in softmax
    const float* Wn  = (const float*)d_in[11];
    const float* bn  = (const float*)d_in[12];
    const float* Wim = (const float*)d_in[13];
    const float* bim = (const float*)d_in[14];
    const float* Wap = (const float*)d_in[15];
    const float* bap = (const float*)d_in[16];
    float* out = (float*)d_out;
    float* ws  = (float*)d_ws;

    // ---- workspace layout (offsets in 4-byte words) ----
    ushort* A2      = (ushort*)(ws + 0);          // [12288][1024] bf16: neigh|h1
    ushort* imgz    = (ushort*)(ws + 6291456);    // [12288][512] bf16
    float*  node_proj = ws + 12582912;            // [12288][256] f32 pre-scaled
    float*  img_proj  = ws + 15728640;            // [2304][256]  f32
    float*  att       = ws + 16318464;            // [12288][36]  f32
    ushort* Z      = (ushort*)(ws + 16760832);    // [2304][512] bf16
    ushort* h_bf   = (ushort*)(ws + 17350656);    // [12288][512] bf16
    ushort* WfnT   = (ushort*)(ws + 20496384);    // [768][512] bf16
    ushort* WiZT   = (ushort*)(ws + 20692992);    // [768][1024] bf16: Wi^T | W'^T
    ushort* Wap1T  = (ushort*)(ws + 21086208);    // [512][512] bf16
    ushort* BT2    = (ushort*)(ws + 21217280);    // [512][1024] bf16: Wap1^T | Wap2^T
    float*  bprime = ws + 21479424;               // [512]
    // zeroed region (contiguous): deg, cur, bcnt, bcur
    int* deg  = (int*)(ws + 21479936);            // [12288]
    int* cur  = deg + N_NODES;                    // [12288]
    int* bcnt = cur + N_NODES;                    // [64]
    int* bcur = bcnt + B_EX;                      // [64]
    int* offs = bcur + B_EX;                      // [12289]
    int* boffs = offs + N_NODES + 1;              // [65]
    int* ssrc = boffs + B_EX + 1;                 // [196608]
    int* nlist = ssrc + E_EDGES;                  // [12288]

    dim3 blk(256);

    // k1: h cvt + weight transposes + zero counters
    preamble<<<dim3(PCVT_BLKS + TR_BLKS + ZERO_BLKS), blk, 0, stream>>>(
        h, h_bf, Wf, Wn, Wi, Wap, WfnT, WiZT, Wap1T, BT2, deg);
    // k2: counting sorts (count phase) || W'^T GEMM
    k2_count_wp<<<dim3(CNT_BLKS + 32), blk, 0, stream>>>(
        dst, batch_ids, deg, bcnt, Wap1T, Wim, WiZT);
    // k3: scans + bprime || [img_proj | Z] GEMM
    k3_scan_imgz<<<dim3(4 + 108), blk, 0, stream>>>(
        deg, offs, bcnt, boffs, bim, Wap, bap, bprime,
        img_feats, WiZT, bi, img_proj, Z);
    // k4: scatter || fused first GEMM (node_proj_s + h1 -> A2)
    k4_scatter_ff<<<dim3(CNT_BLKS + 1152), blk, 0, stream>>>(
        src, dst, offs, cur, ssrc, batch_ids, boffs, bcur, nlist,
        h_bf, WfnT, bf, bn, node_proj, A2);
    // k5: attention softmax || CSR gather -> A2 neigh cols
    k5_att_gather<<<dim3(N_NODES / 4 + N_NODES / 4), blk, 0, stream>>>(
        node_proj, img_proj, batch_ids, Wa, att, offs, ssrc, A2 + H1_OFF, A2 + NEIGH_OFF);
    // k6: attended Z-feature -> imgz bf16
    img_att_batched<<<dim3(B_EX * IA_SLICES), blk, 0, stream>>>(att, Z, boffs, nlist, imgz);
    // k7: out = relu(A2 @ [Wap1; Wap2] + imgz + b')
    gemm_out<<<dim3(8, 96), blk, 0, stream>>>(A2, BT2, bprime, imgz, out);
}

// Round 13
// 208.461 us; speedup vs baseline: 1.2306x; 1.0239x over previous
//
#include <hip/hip_runtime.h>
#include <cstdint>
#include <cstddef>

#define N_NODES 12288
#define B_EX    64
#define R_REG   36
#define E_EDGES 196608
#define DD_IN   512
#define DD_OUT  512
#define P_DIM   256
#define D_IMG   1024
#define TANH_C  2.885390081777927f   // 2*log2(e)

// A2 concatenated GEMM operand: [12288][1024] bf16 : neigh | h1
#define A2_LD     1024
#define NEIGH_OFF 0
#define H1_OFF    512

typedef unsigned short ushort;
typedef __bf16 bf16x8 __attribute__((ext_vector_type(8)));
typedef float f32x4 __attribute__((ext_vector_type(4)));
typedef ushort ushort4v __attribute__((ext_vector_type(4)));
typedef ushort ushort8v __attribute__((ext_vector_type(8)));

__device__ __forceinline__ ushort f2bf(float f) {
    uint32_t u = __float_as_uint(f);
    uint32_t r = (u + 0x7fffu + ((u >> 16) & 1u)) >> 16;
    return (ushort)r;
}
__device__ __forceinline__ float bf2f(ushort u) {
    return __uint_as_float(((uint32_t)u) << 16);
}
__device__ __forceinline__ void gload_lds16(const void* g, void* l) {
    __builtin_amdgcn_global_load_lds((const __attribute__((address_space(1))) void*)g,
                                     (__attribute__((address_space(3))) void*)l, 16, 0, 0);
}
// reg-staged f32 -> bf16 LDS fill (used only in small/latency-tolerant GEMMs)
__device__ __forceinline__ void stage_f32(const float* __restrict__ src, void* ldsDst) {
    float4 v0 = *(const float4*)src;
    float4 v1 = *(const float4*)(src + 4);
    ushort8v o;
    o[0] = f2bf(v0.x); o[1] = f2bf(v0.y); o[2] = f2bf(v0.z); o[3] = f2bf(v0.w);
    o[4] = f2bf(v1.x); o[5] = f2bf(v1.y); o[6] = f2bf(v1.z); o[7] = f2bf(v1.w);
    *(ushort8v*)ldsDst = o;
}
__device__ __forceinline__ float fexp2(float x) {
    float r; asm("v_exp_f32 %0, %1" : "=v"(r) : "v"(x)); return r;
}
__device__ __forceinline__ float frcp(float x) {
    float r; asm("v_rcp_f32 %0, %1" : "=v"(r) : "v"(x)); return r;
}
// bijective XCD swizzle for nwg % 8 == 0 (identity otherwise)
__device__ __forceinline__ int xcd_swz(int lin, int nwg) {
    if ((nwg & 7) == 0) return (lin & 7) * (nwg >> 3) + (lin >> 3);
    return lin;
}

// ======== k1 preamble: h cvt + weight transposes + counter zero ========
#define PCVT_BLKS (N_NODES * DD_IN / 4 / 256)   // 6144
#define TR_BLKS   352
#define ZERO_INTS (2 * N_NODES + 2 * B_EX)      // 24704
#define ZERO_BLKS ((ZERO_INTS + 255) / 256)     // 97
__global__ __launch_bounds__(256) void preamble(
    const float* __restrict__ h, ushort* __restrict__ h_bf,
    const float* __restrict__ Wf, const float* __restrict__ Wn,
    const float* __restrict__ Wi, const float* __restrict__ Wap,
    ushort* __restrict__ WfnT, ushort* __restrict__ WiZT,
    ushort* __restrict__ Wap1T, ushort* __restrict__ BT2,
    int* __restrict__ zero_p)
{
    if (blockIdx.x < PCVT_BLKS) {
        int i = blockIdx.x * 256 + threadIdx.x;
        float4 v = ((const float4*)h)[i];
        ushort4v o;
        o[0] = f2bf(v.x); o[1] = f2bf(v.y); o[2] = f2bf(v.z); o[3] = f2bf(v.w);
        ((ushort4v*)h_bf)[i] = o;
        return;
    }
    if (blockIdx.x >= PCVT_BLKS + TR_BLKS) {
        int i = (blockIdx.x - PCVT_BLKS - TR_BLKS) * 256 + threadIdx.x;
        if (i < ZERO_INTS) zero_p[i] = 0;
        return;
    }
    int t = blockIdx.x - PCVT_BLKS;
    const float* W; ushort* WT; int N, ldt, gx;
    if (t < 32)       { W = Wf;  WT = WfnT;                        N = 256; ldt = 512;  gx = 4; }
    else if (t < 96)  { W = Wn;  WT = WfnT + 256 * 512;            N = 512; ldt = 512;  gx = 8; t -= 32; }
    else if (t < 160) { W = Wi;  WT = WiZT;                        N = 256; ldt = 1024; gx = 4; t -= 96; }
    else if (t < 224) { W = Wap; WT = Wap1T;                       N = 512; ldt = 512;  gx = 8; t -= 160; }
    else if (t < 288) { W = Wap; WT = BT2 + NEIGH_OFF;             N = 512; ldt = 1024; gx = 8; t -= 224; }
    else              { W = Wap + 512 * 512; WT = BT2 + H1_OFF;    N = 512; ldt = 1024; gx = 8; t -= 288; }
    const int n0 = (t % gx) * 64, k0 = (t / gx) * 64;

    __shared__ float tt[64][65];
    const int tx = threadIdx.x & 15, ty = threadIdx.x >> 4;
#pragma unroll
    for (int r = 0; r < 4; ++r) {
        float4 v = *(const float4*)&W[(size_t)(k0 + ty * 4 + r) * N + n0 + tx * 4];
        tt[ty * 4 + r][tx * 4 + 0] = v.x;
        tt[ty * 4 + r][tx * 4 + 1] = v.y;
        tt[ty * 4 + r][tx * 4 + 2] = v.z;
        tt[ty * 4 + r][tx * 4 + 3] = v.w;
    }
    __syncthreads();
    const int nl = threadIdx.x >> 2, kq = (threadIdx.x & 3) * 16;
    ushort u[16] __attribute__((aligned(16)));
#pragma unroll
    for (int c = 0; c < 16; ++c) u[c] = f2bf(tt[kq + c][nl]);
    ushort* d = &WT[(size_t)(n0 + nl) * ldt + k0 + kq];
    *(ushort8v*)d = *(ushort8v*)&u[0];
    *(ushort8v*)(d + 8) = *(ushort8v*)&u[8];
}

// ======== k2: count_all (blocks 0..815) || gemm_wp (blocks 816..847) ========
#define CNT_BLKS (E_EDGES / 256 + N_NODES / 256)   // 816
__global__ __launch_bounds__(256) void k2_count_wp(
    const int* __restrict__ dst, const int* __restrict__ bid,
    int* __restrict__ deg, int* __restrict__ bcnt,
    const ushort* __restrict__ Wap1T, const float* __restrict__ Wim,
    ushort* __restrict__ WiZT)
{
    __shared__ ushort As[128 * 64];
    __shared__ ushort Bs[128 * 64];
    if (blockIdx.x < CNT_BLKS) {
        int b = blockIdx.x;
        if (b < E_EDGES / 256) {
            atomicAdd(&deg[dst[b * 256 + threadIdx.x]], 1);
        } else {
            atomicAdd(&bcnt[bid[(b - E_EDGES / 256) * 256 + threadIdx.x]], 1);
        }
        return;
    }
    const int K = DD_IN;
    const int tid = threadIdx.x;
    const int lane = tid & 63;
    const int wid = tid >> 6;
    const int wm = wid >> 1, wn = wid & 1;
    const int lin = blockIdx.x - CNT_BLKS;
    const int m0 = (lin >> 3) * 128, n0 = (lin & 7) * 128;

    f32x4 acc[4][4] = {};
    const int srow = tid >> 3;
    const int schk = tid & 7;
    const char* AsB = (const char*)As;
    const char* BsB = (const char*)Bs;

    for (int k0 = 0; k0 < K; k0 += 64) {
#pragma unroll
        for (int i = 0; i < 4; ++i) {
            int row = i * 32 + srow;
            int ca = (schk ^ (row & 7)) * 8;
            gload_lds16(Wap1T + (size_t)(m0 + row) * K + k0 + ca,
                        (char*)As + i * 4096 + wid * 1024);
            stage_f32(Wim + (size_t)(n0 + row) * K + k0 + ca,
                      (char*)Bs + i * 4096 + wid * 1024 + lane * 16);
        }
        __syncthreads();
#pragma unroll
        for (int kk = 0; kk < 2; ++kk) {
            const int kc = kk * 4 + (lane >> 4);
            bf16x8 af[4], bfr[4];
#pragma unroll
            for (int i = 0; i < 4; ++i) {
                int row = wm * 64 + i * 16 + (lane & 15);
                af[i] = *(const bf16x8*)(AsB + row * 128 + ((kc ^ (row & 7)) << 4));
            }
#pragma unroll
            for (int j = 0; j < 4; ++j) {
                int col = wn * 64 + j * 16 + (lane & 15);
                bfr[j] = *(const bf16x8*)(BsB + col * 128 + ((kc ^ (col & 7)) << 4));
            }
#pragma unroll
            for (int i = 0; i < 4; ++i)
#pragma unroll
                for (int j = 0; j < 4; ++j)
                    acc[i][j] = __builtin_amdgcn_mfma_f32_16x16x32_bf16(af[i], bfr[j], acc[i][j], 0, 0, 0);
        }
        __syncthreads();
    }

#pragma unroll
    for (int i = 0; i < 4; ++i)
#pragma unroll
        for (int j = 0; j < 4; ++j)
#pragma unroll
            for (int q = 0; q < 4; ++q) {
                int row = m0 + wm * 64 + i * 16 + (lane >> 4) * 4 + q;   // W' col
                int col = n0 + wn * 64 + j * 16 + (lane & 15);           // W' row
                WiZT[(size_t)(256 + row) * D_IMG + col] = f2bf(acc[i][j][q]);
            }
}

// ======== k3: scan_all+bprime (blocks 0..3) || gemm_imgz (blocks 4..111) ========
__global__ __launch_bounds__(256) void k3_scan_imgz(
    const int* __restrict__ deg, int* __restrict__ offs,
    const int* __restrict__ bcnt, int* __restrict__ boffs,
    const float* __restrict__ bim, const float* __restrict__ Wap,
    const float* __restrict__ bap, float* __restrict__ bp,
    const float* __restrict__ imgf, const ushort* __restrict__ WiZT,
    const float* __restrict__ bi, float* __restrict__ img_proj,
    ushort* __restrict__ Z)
{
    __shared__ ushort As[128 * 64];
    __shared__ ushort Bs[128 * 64];
    const int t = threadIdx.x;
    if (blockIdx.x < 4) {
        if (blockIdx.x == 0) {
            __shared__ int s[257];
            const int base = t * 48;
            int sum = 0;
            for (int j = 0; j < 48; ++j) sum += deg[base + j];
            s[t] = sum;
            __syncthreads();
            if (t == 0) {
                int acc = 0;
                for (int i = 0; i < 256; ++i) { int v = s[i]; s[i] = acc; acc += v; }
                s[256] = acc;
            }
            __syncthreads();
            int run = s[t];
            for (int j = 0; j < 48; ++j) { offs[base + j] = run; run += deg[base + j]; }
            if (t == 255) offs[N_NODES] = s[256];
        } else if (blockIdx.x == 1) {
            if (t == 0) {
                int acc = 0;
                for (int i = 0; i < B_EX; ++i) { boffs[i] = acc; acc += bcnt[i]; }
                boffs[B_EX] = acc;
            }
        } else {
            int n = (blockIdx.x - 2) * 256 + t;
            float s = bap[n];
            for (int k = 0; k < DD_OUT; ++k) s += bim[k] * Wap[(size_t)k * DD_OUT + n];
            bp[n] = s;
        }
        return;
    }
    // ---- imgz GEMM: [img_proj | Z] = img_feats @ [Wi | W'] ----
    const int K = D_IMG;
    const int lane = t & 63;
    const int wid = t >> 6;
    const int wm = wid >> 1, wn = wid & 1;
    const int lin = blockIdx.x - 4;
    const int m0 = (lin / 6) * 128, n0 = (lin % 6) * 128;

    f32x4 acc[4][4] = {};
    const int srow = t >> 3;
    const int schk = t & 7;
    const char* AsB = (const char*)As;
    const char* BsB = (const char*)Bs;

    for (int k0 = 0; k0 < K; k0 += 64) {
#pragma unroll
        for (int i = 0; i < 4; ++i) {
            int row = i * 32 + srow;
            int ca = (schk ^ (row & 7)) * 8;
            stage_f32(imgf + (size_t)(m0 + row) * K + k0 + ca,
                      (char*)As + i * 4096 + wid * 1024 + lane * 16);
            gload_lds16(WiZT + (size_t)(n0 + row) * K + k0 + ca,
                        (char*)Bs + i * 4096 + wid * 1024);
        }
        __syncthreads();
#pragma unroll
        for (int kk = 0; kk < 2; ++kk) {
            const int kc = kk * 4 + (lane >> 4);
            bf16x8 af[4], bfr[4];
#pragma unroll
            for (int i = 0; i < 4; ++i) {
                int row = wm * 64 + i * 16 + (lane & 15);
                af[i] = *(const bf16x8*)(AsB + row * 128 + ((kc ^ (row & 7)) << 4));
            }
#pragma unroll
            for (int j = 0; j < 4; ++j) {
                int col = wn * 64 + j * 16 + (lane & 15);
                bfr[j] = *(const bf16x8*)(BsB + col * 128 + ((kc ^ (col & 7)) << 4));
            }
#pragma unroll
            for (int i = 0; i < 4; ++i)
#pragma unroll
                for (int j = 0; j < 4; ++j)
                    acc[i][j] = __builtin_amdgcn_mfma_f32_16x16x32_bf16(af[i], bfr[j], acc[i][j], 0, 0, 0);
        }
        __syncthreads();
    }

    if (n0 < 256) {
#pragma unroll
        for (int i = 0; i < 4; ++i)
#pragma unroll
            for (int j = 0; j < 4; ++j)
#pragma unroll
                for (int q = 0; q < 4; ++q) {
                    int row = m0 + wm * 64 + i * 16 + (lane >> 4) * 4 + q;
                    int col = n0 + wn * 64 + j * 16 + (lane & 15);
                    img_proj[(size_t)row * P_DIM + col] = acc[i][j][q] + bi[col];
                }
    } else {
#pragma unroll
        for (int i = 0; i < 4; ++i)
#pragma unroll
            for (int j = 0; j < 4; ++j)
#pragma unroll
                for (int q = 0; q < 4; ++q) {
                    int row = m0 + wm * 64 + i * 16 + (lane >> 4) * 4 + q;
                    int col = n0 - 256 + wn * 64 + j * 16 + (lane & 15);
                    Z[(size_t)row * DD_OUT + col] = f2bf(acc[i][j][q]);
                }
    }
}

// ======== k4: scatter_all (blocks 0..815) || gemm_fused_first (816..1967) ========
__global__ __launch_bounds__(256) void k4_scatter_ff(
    const int* __restrict__ src, const int* __restrict__ dst,
    const int* __restrict__ offs, int* __restrict__ cur, int* __restrict__ ssrc,
    const int* __restrict__ bid, const int* __restrict__ boffs,
    int* __restrict__ bcur, int* __restrict__ nlist,
    const ushort* __restrict__ h_bf, const ushort* __restrict__ WfnT,
    const float* __restrict__ biasF, const float* __restrict__ biasN,
    float* __restrict__ node_proj_s, ushort* __restrict__ A2)
{
    __shared__ ushort As[128 * 64];
    __shared__ ushort Bs[64 * 64];
    if (blockIdx.x < CNT_BLKS) {
        int b = blockIdx.x;
        if (b < E_EDGES / 256) {
            int i = b * 256 + threadIdx.x;
            int d = dst[i];
            int p = offs[d] + atomicAdd(&cur[d], 1);
            ssrc[p] = src[i];
        } else {
            int i = (b - E_EDGES / 256) * 256 + threadIdx.x;
            int e = bid[i];
            int p = boffs[e] + atomicAdd(&bcur[e], 1);
            nlist[p] = i;
        }
        return;
    }
    // ---- fused first GEMM: BM=128, BN=64, 1152 blocks ----
    const int K = DD_IN;
    const int tid = threadIdx.x;
    const int lane = tid & 63;
    const int wid = tid >> 6;
    const int lin = xcd_swz(blockIdx.x - CNT_BLKS, 1152);
    const int m0 = (lin / 12) * 128, n0 = (lin % 12) * 64;

    f32x4 acc[2][4] = {};
    const int srow = tid >> 3;
    const int schk = tid & 7;
    const char* AsB = (const char*)As;
    const char* BsB = (const char*)Bs;

    for (int k0 = 0; k0 < K; k0 += 64) {
#pragma unroll
        for (int i = 0; i < 4; ++i) {
            int row = i * 32 + srow;
            int ca = (schk ^ (row & 7)) * 8;
            gload_lds16(h_bf + (size_t)(m0 + row) * K + k0 + ca,
                        (char*)As + i * 4096 + wid * 1024);
        }
#pragma unroll
        for (int i = 0; i < 2; ++i) {
            int row = i * 32 + srow;
            int cb = (schk ^ (row & 7)) * 8;
            gload_lds16(WfnT + (size_t)(n0 + row) * K + k0 + cb,
                        (char*)Bs + i * 4096 + wid * 1024);
        }
        __syncthreads();
#pragma unroll
        for (int kk = 0; kk < 2; ++kk) {
            const int kc = kk * 4 + (lane >> 4);
            bf16x8 af[2], bfr[4];
#pragma unroll
            for (int i = 0; i < 2; ++i) {
                int row = wid * 32 + i * 16 + (lane & 15);
                af[i] = *(const bf16x8*)(AsB + row * 128 + ((kc ^ (row & 7)) << 4));
            }
#pragma unroll
            for (int j = 0; j < 4; ++j) {
                int col = j * 16 + (lane & 15);
                bfr[j] = *(const bf16x8*)(BsB + col * 128 + ((kc ^ (col & 7)) << 4));
            }
#pragma unroll
            for (int i = 0; i < 2; ++i)
#pragma unroll
                for (int j = 0; j < 4; ++j)
                    acc[i][j] = __builtin_amdgcn_mfma_f32_16x16x32_bf16(af[i], bfr[j], acc[i][j], 0, 0, 0);
        }
        __syncthreads();
    }

    if (n0 < 256) {
#pragma unroll
        for (int i = 0; i < 2; ++i)
#pragma unroll
            for (int j = 0; j < 4; ++j)
#pragma unroll
                for (int q = 0; q < 4; ++q) {
                    int row = m0 + wid * 32 + i * 16 + (lane >> 4) * 4 + q;
                    int col = n0 + j * 16 + (lane & 15);
                    node_proj_s[(size_t)row * P_DIM + col] = (acc[i][j][q] + biasF[col]) * TANH_C;
                }
    } else {
#pragma unroll
        for (int i = 0; i < 2; ++i)
#pragma unroll
            for (int j = 0; j < 4; ++j)
#pragma unroll
                for (int q = 0; q < 4; ++q) {
                    int row = m0 + wid * 32 + i * 16 + (lane >> 4) * 4 + q;
                    int col = n0 - 256 + j * 16 + (lane & 15);
                    A2[(size_t)row * A2_LD + H1_OFF + col] = f2bf(acc[i][j][q] + biasN[col]);
                }
    }
}

// ======== k5: att_kernel (blocks 0..3071, 4 nodes/block) || gather_neigh (3072..6143) ====
// att LDS: pre-reduced to 16 partials/region via 2x shfl_xor -> red[4][36][20] = 11.5 KB
// (was [4][36][68] = 39 KB which capped the whole kernel, incl. gather blocks, at 4 blk/CU)
__device__ __forceinline__ void acc8(float* a, uint4 v) {
    a[0] += bf2f((ushort)(v.x & 0xffffu)); a[1] += bf2f((ushort)(v.x >> 16));
    a[2] += bf2f((ushort)(v.y & 0xffffu)); a[3] += bf2f((ushort)(v.y >> 16));
    a[4] += bf2f((ushort)(v.z & 0xffffu)); a[5] += bf2f((ushort)(v.z >> 16));
    a[6] += bf2f((ushort)(v.w & 0xffffu)); a[7] += bf2f((ushort)(v.w >> 16));
}

__global__ __launch_bounds__(256) void k5_att_gather(
    const float* __restrict__ node_proj_s, const float* __restrict__ img_proj,
    const int* __restrict__ batch_ids, const float* __restrict__ Wa,
    float* __restrict__ att,
    const int* __restrict__ off, const int* __restrict__ ssrc,
    const ushort* __restrict__ A2h1, ushort* __restrict__ A2nb)
{
    __shared__ float red[4][R_REG][20];
    const int lane = threadIdx.x & 63;
    const int wv = threadIdx.x >> 6;
    if (blockIdx.x < N_NODES / 4) {
        const int n = blockIdx.x * 4 + wv;
        const int b = batch_ids[n];

        const float4 nps = *(const float4*)(node_proj_s + (size_t)n * P_DIM + 4 * lane);
        const float4 wa = *(const float4*)(Wa + 4 * lane);
        const float* ip0 = img_proj + (size_t)b * R_REG * P_DIM + 4 * lane;

#pragma unroll
        for (int r = 0; r < R_REG; ++r) {
            float4 ip = *(const float4*)(ip0 + (size_t)r * P_DIM);
            float t0 = fexp2(fmaf(ip.x, TANH_C, nps.x));
            float t1 = fexp2(fmaf(ip.y, TANH_C, nps.y));
            float t2 = fexp2(fmaf(ip.z, TANH_C, nps.z));
            float t3 = fexp2(fmaf(ip.w, TANH_C, nps.w));
            float p;
            p = wa.x * frcp(t0 + 1.f);
            p = fmaf(wa.y, frcp(t1 + 1.f), p);
            p = fmaf(wa.z, frcp(t2 + 1.f), p);
            p = fmaf(wa.w, frcp(t3 + 1.f), p);
            // pre-reduce across 4 lane groups: lanes 0..15 hold sum of l, l+16, l+32, l+48
            p += __shfl_xor(p, 16);
            p += __shfl_xor(p, 32);
            if (lane < 16) red[wv][r][lane] = p;
        }
        __syncthreads();

        float logit = -INFINITY;
        if (lane < R_REG) {
            const float* row = &red[wv][lane][0];
            float4 a = *(const float4*)row;
            float4 bq = *(const float4*)(row + 4);
            float4 c = *(const float4*)(row + 8);
            float4 d = *(const float4*)(row + 12);
            float s01 = ((a.x + a.y) + (a.z + a.w)) + ((bq.x + bq.y) + (bq.z + bq.w));
            float s23 = ((c.x + c.y) + (c.z + c.w)) + ((d.x + d.y) + (d.z + d.w));
            logit = -2.f * (s01 + s23);
        }
        float m = logit;
#pragma unroll
        for (int o = 32; o; o >>= 1) m = fmaxf(m, __shfl_xor(m, o));
        float e = (lane < R_REG) ? __expf(logit - m) : 0.f;
        float s = e;
#pragma unroll
        for (int o = 32; o; o >>= 1) s += __shfl_xor(s, o);
        if (lane < R_REG) att[(size_t)n * R_REG + lane] = e / s;
        return;
    }
    // ---- gather: wave per node, lane = 8 cols (uint4), unroll x2 ----
    const int n = (blockIdx.x - N_NODES / 4) * 4 + wv;
    const int e0 = off[n], e1 = off[n + 1];

    float a[8] = {};
    int e = e0;
    for (; e + 2 <= e1; e += 2) {
        int s0 = ssrc[e], s1 = ssrc[e + 1];
        uint4 v0 = *(const uint4*)(A2h1 + (size_t)s0 * A2_LD + lane * 8);
        uint4 v1 = *(const uint4*)(A2h1 + (size_t)s1 * A2_LD + lane * 8);
        acc8(a, v0);
        acc8(a, v1);
    }
    if (e < e1) {
        int s0 = ssrc[e];
        uint4 v0 = *(const uint4*)(A2h1 + (size_t)s0 * A2_LD + lane * 8);
        acc8(a, v0);
    }
    ushort8v o;
#pragma unroll
    for (int i = 0; i < 8; ++i) o[i] = f2bf(a[i]);
    *(ushort8v*)(A2nb + (size_t)n * A2_LD + lane * 8) = o;
}

// ======= k6: batched attended Z-feature: imgz[n] = sum_r att[n][r]*Z[b][r] (bf16 out) ====
#define IA_SLICES 16
__global__ __launch_bounds__(256) void img_att_batched(
    const float* __restrict__ att, const ushort* __restrict__ Z,
    const int* __restrict__ boffs, const int* __restrict__ nlist,
    ushort* __restrict__ imgz)
{
    const int b     = blockIdx.x & 63;
    const int slice = blockIdx.x >> 6;
    const int t = threadIdx.x;
    const int c0 = 2 * t;

    const int ns = boffs[b], ne = boffs[b + 1];
    const int cnt = ne - ns;
    const int per = (cnt + IA_SLICES - 1) / IA_SLICES;
    const int i0 = ns + slice * per;
    const int i1 = min(i0 + per, ne);
    if (i0 >= i1) return;

    float2 col[R_REG];
    const ushort* base = Z + (size_t)b * R_REG * DD_OUT + c0;
#pragma unroll
    for (int r = 0; r < R_REG; ++r) {
        ushort2 u = *(const ushort2*)(base + (size_t)r * DD_OUT);
        col[r].x = bf2f(u.x); col[r].y = bf2f(u.y);
    }

    __shared__ float att_s[8][R_REG];
    for (int i = i0; i < i1; i += 8) {
        int g = min(8, i1 - i);
        __syncthreads();
        for (int idx = t; idx < g * R_REG; idx += 256) {
            int j = idx / R_REG, r = idx - j * R_REG;
            att_s[j][r] = att[(size_t)nlist[i + j] * R_REG + r];
        }
        __syncthreads();
        for (int j = 0; j < g; ++j) {
            float4 av[9];
#pragma unroll
            for (int q = 0; q < 9; ++q) av[q] = *(const float4*)&att_s[j][q * 4];
            float ax = 0.f, ay = 0.f;
#pragma unroll
            for (int r = 0; r < R_REG; ++r) {
                float a = (r & 2) ? ((r & 1) ? av[r >> 2].w : av[r >> 2].z)
                                  : ((r & 1) ? av[r >> 2].y : av[r >> 2].x);
                ax += a * col[r].x;
                ay += a * col[r].y;
            }
            ushort2 o; o.x = f2bf(ax); o.y = f2bf(ay);
            *(ushort2*)&imgz[(size_t)nlist[i + j] * DD_OUT + c0] = o;
        }
    }
}

// ======== k7: final GEMM: out = relu(A2 @ BT2^T + imgz + b'), BM=128 BN=64, K=1024 ====
__global__ __launch_bounds__(256) void gemm_out(
    const ushort* __restrict__ A, const ushort* __restrict__ BT,
    const float* __restrict__ bias, const ushort* __restrict__ Cadd,
    float* __restrict__ Cf)
{
    __shared__ ushort As[128 * 64];
    __shared__ ushort Bs[64 * 64];
    const int K = A2_LD;
    const int tid = threadIdx.x;
    const int lane = tid & 63;
    const int wid = tid >> 6;
    const int lin = xcd_swz(blockIdx.y * 8 + blockIdx.x, 768);
    const int m0 = (lin >> 3) * 128, n0 = (lin & 7) * 64;

    f32x4 acc[2][4] = {};
    const int srow = tid >> 3;
    const int schk = tid & 7;
    const char* AsB = (const char*)As;
    const char* BsB = (const char*)Bs;

    for (int k0 = 0; k0 < K; k0 += 64) {
#pragma unroll
        for (int i = 0; i < 4; ++i) {
            int row = i * 32 + srow;
            int ca = (schk ^ (row & 7)) * 8;
            gload_lds16(A + (size_t)(m0 + row) * K + k0 + ca,
                        (char*)As + i * 4096 + wid * 1024);
        }
#pragma unroll
        for (int i = 0; i < 2; ++i) {
            int row = i * 32 + srow;
            int cb = (schk ^ (row & 7)) * 8;
            gload_lds16(BT + (size_t)(n0 + row) * K + k0 + cb,
                        (char*)Bs + i * 4096 + wid * 1024);
        }
        __syncthreads();
#pragma unroll
        for (int kk = 0; kk < 2; ++kk) {
            const int kc = kk * 4 + (lane >> 4);
            bf16x8 af[2], bfr[4];
#pragma unroll
            for (int i = 0; i < 2; ++i) {
                int row = wid * 32 + i * 16 + (lane & 15);
                af[i] = *(const bf16x8*)(AsB + row * 128 + ((kc ^ (row & 7)) << 4));
            }
#pragma unroll
            for (int j = 0; j < 4; ++j) {
                int col = j * 16 + (lane & 15);
                bfr[j] = *(const bf16x8*)(BsB + col * 128 + ((kc ^ (col & 7)) << 4));
            }
#pragma unroll
            for (int i = 0; i < 2; ++i)
#pragma unroll
                for (int j = 0; j < 4; ++j)
                    acc[i][j] = __builtin_amdgcn_mfma_f32_16x16x32_bf16(af[i], bfr[j], acc[i][j], 0, 0, 0);
        }
        __syncthreads();
    }

#pragma unroll
    for (int i = 0; i < 2; ++i)
#pragma unroll
        for (int j = 0; j < 4; ++j)
#pragma unroll
            for (int q = 0; q < 4; ++q) {
                int row = m0 + wid * 32 + i * 16 + (lane >> 4) * 4 + q;
                int col = n0 + j * 16 + (lane & 15);
                float v = acc[i][j][q] + bias[col] + bf2f(Cadd[(size_t)row * DD_OUT + col]);
                Cf[(size_t)row * DD_OUT + col] = fmaxf(v, 0.f);
            }
}

extern "C" void kernel_launch(void* const* d_in, const int* in_sizes, int n_in,
                              void* d_out, int out_size, void* d_ws, size_t ws_size,
                              hipStream_t stream) {
    const float* h         = (const float*)d_in[0];
    const float* img_feats = (const float*)d_in[1];
    const int*   batch_ids = (const int*)d_in[2];
    const int*   src       = (const int*)d_in[3];
    const int*   dst       = (const int*)d_in[4];
    const float* Wf  = (const float*)d_in[5];
    const float* bf  = (const float*)d_in[6];
    const float* Wi  = (const float*)d_in[7];
    const float* bi  = (const float*)d_in[8];
    const float* Wa  = (const float*)d_in[9];
    // d_in[10] = ba: constant logit shift, cancels in softmax
    const float* Wn  = (const float*)d_in[11];
    const float* bn  = (const float*)d_in[12];
    const float* Wim = (const float*)d_in[13];
    const float* bim = (const float*)d_in[14];
    const float* Wap = (const float*)d_in[15];
    const float* bap = (const float*)d_in[16];
    float* out = (float*)d_out;
    float* ws  = (float*)d_ws;

    // ---- workspace layout (offsets in 4-byte words) ----
    ushort* A2      = (ushort*)(ws + 0);          // [12288][1024] bf16: neigh|h1
    ushort* imgz    = (ushort*)(ws + 6291456);    // [12288][512] bf16
    float*  node_proj = ws + 12582912;            // [12288][256] f32 pre-scaled
    float*  img_proj  = ws + 15728640;            // [2304][256]  f32
    float*  att       = ws + 16318464;            // [12288][36]  f32
    ushort* Z      = (ushort*)(ws + 16760832);    // [2304][512] bf16
    ushort* h_bf   = (ushort*)(ws + 17350656);    // [12288][512] bf16
    ushort* WfnT   = (ushort*)(ws + 20496384);    // [768][512] bf16
    ushort* WiZT   = (ushort*)(ws + 20692992);    // [768][1024] bf16: Wi^T | W'^T
    ushort* Wap1T  = (ushort*)(ws + 21086208);    // [512][512] bf16
    ushort* BT2    = (ushort*)(ws + 21217280);    // [512][1024] bf16: Wap1^T | Wap2^T
    float*  bprime = ws + 21479424;               // [512]
    // zeroed region (contiguous): deg, cur, bcnt, bcur
    int* deg  = (int*)(ws + 21479936);            // [12288]
    int* cur  = deg + N_NODES;                    // [12288]
    int* bcnt = cur + N_NODES;                    // [64]
    int* bcur = bcnt + B_EX;                      // [64]
    int* offs = bcur + B_EX;                      // [12289]
    int* boffs = offs + N_NODES + 1;              // [65]
    int* ssrc = boffs + B_EX + 1;                 // [196608]
    int* nlist = ssrc + E_EDGES;                  // [12288]

    dim3 blk(256);

    // k1: h cvt + weight transposes + zero counters
    preamble<<<dim3(PCVT_BLKS + TR_BLKS + ZERO_BLKS), blk, 0, stream>>>(
        h, h_bf, Wf, Wn, Wi, Wap, WfnT, WiZT, Wap1T, BT2, deg);
    // k2: counting sorts (count phase) || W'^T GEMM
    k2_count_wp<<<dim3(CNT_BLKS + 32), blk, 0, stream>>>(
        dst, batch_ids, deg, bcnt, Wap1T, Wim, WiZT);
    // k3: scans + bprime || [img_proj | Z] GEMM
    k3_scan_imgz<<<dim3(4 + 108), blk, 0, stream>>>(
        deg, offs, bcnt, boffs, bim, Wap, bap, bprime,
        img_feats, WiZT, bi, img_proj, Z);
    // k4: scatter || fused first GEMM (node_proj_s + h1 -> A2)
    k4_scatter_ff<<<dim3(CNT_BLKS + 1152), blk, 0, stream>>>(
        src, dst, offs, cur, ssrc, batch_ids, boffs, bcur, nlist,
        h_bf, WfnT, bf, bn, node_proj, A2);
    // k5: attention softmax || CSR gather -> A2 neigh cols
    k5_att_gather<<<dim3(N_NODES / 4 + N_NODES / 4), blk, 0, stream>>>(
        node_proj, img_proj, batch_ids, Wa, att, offs, ssrc, A2 + H1_OFF, A2 + NEIGH_OFF);
    // k6: attended Z-feature -> imgz bf16
    img_att_batched<<<dim3(B_EX * IA_SLICES), blk, 0, stream>>>(att, Z, boffs, nlist, imgz);
    // k7: out = relu(A2 @ [Wap1; Wap2] + imgz + b')
    gemm_out<<<dim3(8, 96), blk, 0, stream>>>(A2, BT2, bprime, imgz, out);
}